// Round 1
// baseline (1158.507 us; speedup 1.0000x reference)
//
#include <hip/hip_runtime.h>
#include <math.h>

#define N_NODES 40000
#define N_EDGES 640000
#define N_GRAPH 64
#define HEADS 4
#define CHAN 64
#define HC 256          // HEADS*CHAN
#define F_IN 256
#define NHID 1024
#define NOUT 768
#define E_TOT (N_EDGES + N_NODES)

// ---------------- CSR build ----------------

__global__ void count_deg_kernel(const int* __restrict__ ei, int* __restrict__ deg) {
    int i = blockIdx.x * blockDim.x + threadIdx.x;
    if (i >= E_TOT) return;
    int dst = (i < N_EDGES) ? ei[N_EDGES + i] : (i - N_EDGES);
    atomicAdd(&deg[dst], 1);
}

__global__ __launch_bounds__(1024)
void scan_kernel(const int* __restrict__ deg, int* __restrict__ rowptr) {
    __shared__ int s[1024];
    __shared__ int carry;
    const int t = threadIdx.x;
    if (t == 0) carry = 0;
    __syncthreads();
    for (int base = 0; base < N_NODES; base += 1024) {
        int i = base + t;
        int v = (i < N_NODES) ? deg[i] : 0;
        s[t] = v;
        __syncthreads();
        #pragma unroll
        for (int off = 1; off < 1024; off <<= 1) {
            int x = (t >= off) ? s[t - off] : 0;
            __syncthreads();
            s[t] += x;
            __syncthreads();
        }
        if (i < N_NODES) rowptr[i] = carry + s[t] - v;
        __syncthreads();               // everyone has read carry
        if (t == 1023) carry += s[1023];
        __syncthreads();               // carry updated before next chunk
    }
    if (t == 0) rowptr[N_NODES] = carry;
}

__global__ void fill_csr_kernel(const int* __restrict__ ei, const int* __restrict__ rowptr,
                                int* __restrict__ cursor, int* __restrict__ csr_src) {
    int i = blockIdx.x * blockDim.x + threadIdx.x;
    if (i >= E_TOT) return;
    int src, dst;
    if (i < N_EDGES) { src = ei[i]; dst = ei[N_EDGES + i]; }
    else             { src = dst = i - N_EDGES; }
    int pos = atomicAdd(&cursor[dst], 1);
    csr_src[rowptr[dst] + pos] = src;
}

// ---------------- fp32 GEMM: C[n,m] = sum_k A[n,k] * B[k,m], K=M=256 ----------------

#define GBM 128
#define GBN 64
#define GBK 32

__global__ __launch_bounds__(256)
void gemm_kernel(const float* __restrict__ A, const float* __restrict__ B,
                 float* __restrict__ C, int nrows) {
    __shared__ float As[GBK][GBM + 4];
    __shared__ float Bs[GBK][GBN];
    const int tid = threadIdx.x;
    const int tm = tid & 15;    // rows tm*8 .. tm*8+7
    const int tn = tid >> 4;    // cols tn*4 .. tn*4+3
    const int row0 = blockIdx.x * GBM;
    const int col0 = blockIdx.y * GBN;

    float acc[8][4];
    #pragma unroll
    for (int r = 0; r < 8; r++)
        #pragma unroll
        for (int c = 0; c < 4; c++) acc[r][c] = 0.f;

    for (int kt = 0; kt < 256; kt += GBK) {
        #pragma unroll
        for (int i = 0; i < 4; i++) {
            int id = tid + i * 256;
            int rl = id >> 3;          // 0..127
            int kq = id & 7;           // *4 within K-tile
            int arow = row0 + rl;
            if (arow >= nrows) arow = nrows - 1;   // clamp (guarded store later)
            float4 v = *reinterpret_cast<const float4*>(&A[(size_t)arow * 256 + kt + kq * 4]);
            As[kq * 4 + 0][rl] = v.x;
            As[kq * 4 + 1][rl] = v.y;
            As[kq * 4 + 2][rl] = v.z;
            As[kq * 4 + 3][rl] = v.w;
        }
        #pragma unroll
        for (int i = 0; i < 2; i++) {
            int id = tid + i * 256;
            int br = id >> 4;          // 0..31
            int bc = id & 15;          // *4 cols
            float4 v = *reinterpret_cast<const float4*>(&B[(size_t)(kt + br) * 256 + col0 + bc * 4]);
            *reinterpret_cast<float4*>(&Bs[br][bc * 4]) = v;
        }
        __syncthreads();
        #pragma unroll
        for (int kk = 0; kk < GBK; ++kk) {
            float4 a0 = *reinterpret_cast<const float4*>(&As[kk][tm * 8]);
            float4 a1 = *reinterpret_cast<const float4*>(&As[kk][tm * 8 + 4]);
            float4 b  = *reinterpret_cast<const float4*>(&Bs[kk][tn * 4]);
            float av[8] = {a0.x, a0.y, a0.z, a0.w, a1.x, a1.y, a1.z, a1.w};
            float bv[4] = {b.x, b.y, b.z, b.w};
            #pragma unroll
            for (int r = 0; r < 8; r++)
                #pragma unroll
                for (int c = 0; c < 4; c++)
                    acc[r][c] = fmaf(av[r], bv[c], acc[r][c]);
        }
        __syncthreads();
    }
    #pragma unroll
    for (int r = 0; r < 8; r++) {
        int row = row0 + tm * 8 + r;
        if (row < nrows) {
            float4 st = make_float4(acc[r][0], acc[r][1], acc[r][2], acc[r][3]);
            *reinterpret_cast<float4*>(&C[(size_t)row * 256 + col0 + tn * 4]) = st;
        }
    }
}

// ---------------- per-node attention scalars ----------------
// one 64-lane wave per node; 4 nodes per 256-thread block

__global__ void alpha_kernel(const float* __restrict__ h, const float* __restrict__ a_s,
                             const float* __restrict__ a_d, float* __restrict__ asrc,
                             float* __restrict__ adst) {
    int lane = threadIdx.x & 63;
    int node = blockIdx.x * 4 + (threadIdx.x >> 6);
    if (node >= N_NODES) return;
    float4 v  = *reinterpret_cast<const float4*>(&h[(size_t)node * 256 + lane * 4]);
    float4 ws = *reinterpret_cast<const float4*>(&a_s[lane * 4]);
    float4 wd = *reinterpret_cast<const float4*>(&a_d[lane * 4]);
    float ps = v.x * ws.x + v.y * ws.y + v.z * ws.z + v.w * ws.w;
    float pd = v.x * wd.x + v.y * wd.y + v.z * wd.z + v.w * wd.w;
    #pragma unroll
    for (int off = 1; off < 16; off <<= 1) {
        ps += __shfl_xor(ps, off, 64);
        pd += __shfl_xor(pd, off, 64);
    }
    if ((lane & 15) == 0) {
        int head = lane >> 4;
        asrc[node * 4 + head] = ps;
        adst[node * 4 + head] = pd;
    }
}

// ---------------- fused edge softmax + aggregation (gather, online softmax) ----------------
// one block (256 threads = H*C channels) per dst node

__global__ void gat_aggregate(const float* __restrict__ h, const float* __restrict__ asrc,
                              const float* __restrict__ adst, const int* __restrict__ rowptr,
                              const int* __restrict__ csr_src, const float* __restrict__ bias,
                              float* __restrict__ out, int do_relu) {
    const int n = blockIdx.x;
    const int t = threadIdx.x;
    const int head = t >> 6;
    const int start = rowptr[n];
    const int end = rowptr[n + 1];
    const float adst_n = adst[n * 4 + head];

    float m = -INFINITY, s = 0.f, acc = 0.f;
    for (int e = start; e < end; ++e) {
        int src = csr_src[e];
        float sc = asrc[src * 4 + head] + adst_n;
        sc = (sc >= 0.f) ? sc : 0.2f * sc;          // leaky relu 0.2
        float nm = fmaxf(m, sc);
        float scale = __expf(m - nm);               // 0 on first iter
        float w = __expf(sc - nm);
        s = s * scale + w;
        acc = acc * scale + w * h[(size_t)src * 256 + t];
        m = nm;
    }
    float r = acc / s + bias[t];
    if (do_relu) r = fmaxf(r, 0.f);
    out[(size_t)n * 256 + t] = r;
}

// ---------------- pooling (batch is sorted) ----------------

__global__ void count_kernel(const int* __restrict__ batch, int* __restrict__ cnt) {
    int i = blockIdx.x * blockDim.x + threadIdx.x;
    if (i < N_NODES) atomicAdd(&cnt[batch[i]], 1);
}

__global__ void pool_kernel(const float* __restrict__ h, const int* __restrict__ batch,
                            float* __restrict__ pooled) {
    const int t = threadIdx.x;       // channel
    const int n0 = blockIdx.x * 256;
    if (n0 >= N_NODES) return;
    const int nend = min(n0 + 256, N_NODES);
    float acc = 0.f;
    int cur = batch[n0];
    for (int n = n0; n < nend; ++n) {
        int g = batch[n];
        if (g != cur) {
            atomicAdd(&pooled[cur * 256 + t], acc);
            acc = 0.f;
            cur = g;
        }
        acc += h[(size_t)n * 256 + t];
    }
    atomicAdd(&pooled[cur * 256 + t], acc);
}

// ---------------- MLP head ----------------

__global__ __launch_bounds__(1024)
void mlp1_kernel(const float* __restrict__ pooled, const int* __restrict__ cnt,
                 const float* __restrict__ W, const float* __restrict__ b,
                 float* __restrict__ hidden) {
    __shared__ float row[256];
    const int g = blockIdx.x, t = threadIdx.x;
    if (t < 256) {
        float c = (float)max(cnt[g], 1);
        row[t] = pooled[g * 256 + t] / c;
    }
    __syncthreads();
    float acc = b[t];
    for (int k = 0; k < 256; k++) acc = fmaf(row[k], W[(size_t)k * NHID + t], acc);
    hidden[g * NHID + t] = fmaxf(acc, 0.f);
}

__global__ __launch_bounds__(768)
void mlp2_kernel(const float* __restrict__ hidden, const float* __restrict__ W,
                 const float* __restrict__ b, float* __restrict__ out) {
    __shared__ float row[NHID];
    const int g = blockIdx.x, t = threadIdx.x;
    row[t] = hidden[g * NHID + t];
    if (t < NHID - NOUT) row[NOUT + t] = hidden[g * NHID + NOUT + t];
    __syncthreads();
    float acc = b[t];
    for (int k = 0; k < NHID; k++) acc = fmaf(row[k], W[(size_t)k * NOUT + t], acc);
    out[g * NOUT + t] = acc;
}

// ---------------- launch ----------------

extern "C" void kernel_launch(void* const* d_in, const int* in_sizes, int n_in,
                              void* d_out, int out_size, void* d_ws, size_t ws_size,
                              hipStream_t stream) {
    const float* x  = (const float*)d_in[0];
    const int* ei   = (const int*)d_in[1];
    const int* batch = (const int*)d_in[2];
    const float* W1 = (const float*)d_in[3];
    const float* as1 = (const float*)d_in[4];
    const float* ad1 = (const float*)d_in[5];
    const float* b1 = (const float*)d_in[6];
    const float* W2 = (const float*)d_in[7];
    const float* as2 = (const float*)d_in[8];
    const float* ad2 = (const float*)d_in[9];
    const float* b2 = (const float*)d_in[10];
    const float* W3 = (const float*)d_in[11];
    const float* as3 = (const float*)d_in[12];
    const float* ad3 = (const float*)d_in[13];
    const float* b3 = (const float*)d_in[14];
    const float* Wm1 = (const float*)d_in[15];
    const float* bm1 = (const float*)d_in[16];
    const float* Wm2 = (const float*)d_in[17];
    const float* bm2 = (const float*)d_in[18];
    float* out = (float*)d_out;

    // workspace layout (256B aligned)
    char* base = (char*)d_ws;
    size_t off = 0;
    auto alloc = [&](size_t bytes) { char* p = base + off; off = (off + bytes + 255) & ~(size_t)255; return p; };
    float* bufA   = (float*)alloc((size_t)N_NODES * 256 * 4);
    float* bufB   = (float*)alloc((size_t)N_NODES * 256 * 4);
    float* asrc   = (float*)alloc((size_t)N_NODES * 4 * 4);
    float* adst   = (float*)alloc((size_t)N_NODES * 4 * 4);
    int*   deg    = (int*)alloc((size_t)N_NODES * 4);
    int*   cursor = (int*)alloc((size_t)N_NODES * 4);
    int*   rowptr = (int*)alloc((size_t)(N_NODES + 1) * 4);
    int*   csrsrc = (int*)alloc((size_t)E_TOT * 4);
    float* pooled = (float*)alloc((size_t)N_GRAPH * 256 * 4);
    int*   cnt    = (int*)alloc((size_t)N_GRAPH * 4);
    float* hidden = (float*)alloc((size_t)N_GRAPH * NHID * 4);
    (void)ws_size; (void)n_in; (void)in_sizes; (void)out_size;

    // zero accumulators (captured each replay)
    hipMemsetAsync(deg, 0, (size_t)N_NODES * 4, stream);
    hipMemsetAsync(cursor, 0, (size_t)N_NODES * 4, stream);
    hipMemsetAsync(pooled, 0, (size_t)N_GRAPH * 256 * 4, stream);
    hipMemsetAsync(cnt, 0, (size_t)N_GRAPH * 4, stream);

    const int eb = (E_TOT + 255) / 256;
    count_deg_kernel<<<eb, 256, 0, stream>>>(ei, deg);
    scan_kernel<<<1, 1024, 0, stream>>>(deg, rowptr);
    fill_csr_kernel<<<eb, 256, 0, stream>>>(ei, rowptr, cursor, csrsrc);

    dim3 ggrid((N_NODES + GBM - 1) / GBM, 256 / GBN);

    // layer 1
    gemm_kernel<<<ggrid, 256, 0, stream>>>(x, W1, bufA, N_NODES);
    alpha_kernel<<<N_NODES / 4, 256, 0, stream>>>(bufA, as1, ad1, asrc, adst);
    gat_aggregate<<<N_NODES, 256, 0, stream>>>(bufA, asrc, adst, rowptr, csrsrc, b1, bufB, 1);
    // layer 2
    gemm_kernel<<<ggrid, 256, 0, stream>>>(bufB, W2, bufA, N_NODES);
    alpha_kernel<<<N_NODES / 4, 256, 0, stream>>>(bufA, as2, ad2, asrc, adst);
    gat_aggregate<<<N_NODES, 256, 0, stream>>>(bufA, asrc, adst, rowptr, csrsrc, b2, bufB, 1);
    // layer 3
    gemm_kernel<<<ggrid, 256, 0, stream>>>(bufB, W3, bufA, N_NODES);
    alpha_kernel<<<N_NODES / 4, 256, 0, stream>>>(bufA, as3, ad3, asrc, adst);
    gat_aggregate<<<N_NODES, 256, 0, stream>>>(bufA, asrc, adst, rowptr, csrsrc, b3, bufB, 0);

    // pool + MLP
    count_kernel<<<(N_NODES + 255) / 256, 256, 0, stream>>>(batch, cnt);
    pool_kernel<<<(N_NODES + 255) / 256, 256, 0, stream>>>(bufB, batch, pooled);
    mlp1_kernel<<<N_GRAPH, 1024, 0, stream>>>(pooled, cnt, Wm1, bm1, hidden);
    mlp2_kernel<<<N_GRAPH, NOUT, 0, stream>>>(hidden, Wm2, bm2, out);
}

// Round 2
// 958.464 us; speedup vs baseline: 1.2087x; 1.2087x over previous
//
#include <hip/hip_runtime.h>
#include <math.h>

#define N_NODES 40000
#define N_EDGES 640000
#define N_GRAPH 64
#define HEADS 4
#define CHAN 64
#define HC 256          // HEADS*CHAN
#define F_IN 256
#define NHID 1024
#define NOUT 768
#define E_TOT (N_EDGES + N_NODES)

// ---------------- CSR build ----------------

__global__ void count_deg_kernel(const int* __restrict__ ei, int* __restrict__ deg) {
    int i = blockIdx.x * blockDim.x + threadIdx.x;
    if (i >= E_TOT) return;
    int dst = (i < N_EDGES) ? ei[N_EDGES + i] : (i - N_EDGES);
    atomicAdd(&deg[dst], 1);
}

// single block: thread-serial partials + one 1024-wide scan (21 barriers total)
__global__ __launch_bounds__(1024)
void scan_kernel(const int* __restrict__ deg, int* __restrict__ rowptr) {
    __shared__ int s[1024];
    const int t = threadIdx.x;
    const int chunk = (N_NODES + 1023) / 1024;   // 40
    const int base = t * chunk;
    int sum = 0;
    for (int i = 0; i < chunk; i++) {
        int idx = base + i;
        if (idx < N_NODES) sum += deg[idx];
    }
    s[t] = sum;
    __syncthreads();
    #pragma unroll
    for (int off = 1; off < 1024; off <<= 1) {
        int x = (t >= off) ? s[t - off] : 0;
        __syncthreads();
        s[t] += x;
        __syncthreads();
    }
    int run = (t > 0) ? s[t - 1] : 0;            // exclusive prefix for this chunk
    for (int i = 0; i < chunk; i++) {
        int idx = base + i;
        if (idx < N_NODES) { rowptr[idx] = run; run += deg[idx]; }
    }
    if (t == 1023) rowptr[N_NODES] = s[1023];
}

__global__ void fill_csr_kernel(const int* __restrict__ ei, const int* __restrict__ rowptr,
                                int* __restrict__ cursor, int* __restrict__ csr_src) {
    int i = blockIdx.x * blockDim.x + threadIdx.x;
    if (i >= E_TOT) return;
    int src, dst;
    if (i < N_EDGES) { src = ei[i]; dst = ei[N_EDGES + i]; }
    else             { src = dst = i - N_EDGES; }
    int pos = atomicAdd(&cursor[dst], 1);
    csr_src[rowptr[dst] + pos] = src;
}

// ---------------- fp32 GEMM + fused alpha epilogue ----------------
// C[n,m] = sum_k A[n,k] * B[k,m], K=M=256. blockIdx.y == head (GBN==CHAN==64).
// Epilogue: asrc[n,head] = sum_c C[n, head*64+c] * a_s[head,c]  (same for adst)

#define GBM 128
#define GBN 64
#define GBK 32

__global__ __launch_bounds__(256)
void gemm_kernel(const float* __restrict__ A, const float* __restrict__ B,
                 float* __restrict__ C, int nrows,
                 const float* __restrict__ a_s, const float* __restrict__ a_d,
                 float* __restrict__ asrc, float* __restrict__ adst) {
    __shared__ float As[GBK][GBM + 4];
    __shared__ float Bs[GBK][GBN];
    const int tid = threadIdx.x;
    const int tm = tid >> 4;    // rows tm*8 .. tm*8+7   (16 row-groups)
    const int tn = tid & 15;    // cols tn*4 .. tn*4+3   (16 col-groups, within a 16-lane shfl group)
    const int row0 = blockIdx.x * GBM;
    const int col0 = blockIdx.y * GBN;

    float acc[8][4];
    #pragma unroll
    for (int r = 0; r < 8; r++)
        #pragma unroll
        for (int c = 0; c < 4; c++) acc[r][c] = 0.f;

    for (int kt = 0; kt < 256; kt += GBK) {
        #pragma unroll
        for (int i = 0; i < 4; i++) {
            int id = tid + i * 256;
            int rl = id >> 3;          // 0..127
            int kq = id & 7;           // *4 within K-tile
            int arow = row0 + rl;
            if (arow >= nrows) arow = nrows - 1;   // clamp (guarded store later)
            float4 v = *reinterpret_cast<const float4*>(&A[(size_t)arow * 256 + kt + kq * 4]);
            As[kq * 4 + 0][rl] = v.x;
            As[kq * 4 + 1][rl] = v.y;
            As[kq * 4 + 2][rl] = v.z;
            As[kq * 4 + 3][rl] = v.w;
        }
        #pragma unroll
        for (int i = 0; i < 2; i++) {
            int id = tid + i * 256;
            int br = id >> 4;          // 0..31
            int bc = id & 15;          // *4 cols
            float4 v = *reinterpret_cast<const float4*>(&B[(size_t)(kt + br) * 256 + col0 + bc * 4]);
            *reinterpret_cast<float4*>(&Bs[br][bc * 4]) = v;
        }
        __syncthreads();
        #pragma unroll
        for (int kk = 0; kk < GBK; ++kk) {
            float4 a0 = *reinterpret_cast<const float4*>(&As[kk][tm * 8]);      // broadcast in 16-group
            float4 a1 = *reinterpret_cast<const float4*>(&As[kk][tm * 8 + 4]);
            float4 b  = *reinterpret_cast<const float4*>(&Bs[kk][tn * 4]);      // 2-way (free)
            float av[8] = {a0.x, a0.y, a0.z, a0.w, a1.x, a1.y, a1.z, a1.w};
            float bv[4] = {b.x, b.y, b.z, b.w};
            #pragma unroll
            for (int r = 0; r < 8; r++)
                #pragma unroll
                for (int c = 0; c < 4; c++)
                    acc[r][c] = fmaf(av[r], bv[c], acc[r][c]);
        }
        __syncthreads();
    }

    const int head = blockIdx.y;
    float4 was = *reinterpret_cast<const float4*>(&a_s[head * 64 + tn * 4]);
    float4 wad = *reinterpret_cast<const float4*>(&a_d[head * 64 + tn * 4]);
    #pragma unroll
    for (int r = 0; r < 8; r++) {
        int row = row0 + tm * 8 + r;
        // per-row alpha partials, reduced across the 16 col-groups (one 16-lane shfl group)
        float ps = acc[r][0] * was.x + acc[r][1] * was.y + acc[r][2] * was.z + acc[r][3] * was.w;
        float pd = acc[r][0] * wad.x + acc[r][1] * wad.y + acc[r][2] * wad.z + acc[r][3] * wad.w;
        #pragma unroll
        for (int off = 1; off < 16; off <<= 1) {
            ps += __shfl_xor(ps, off, 16);
            pd += __shfl_xor(pd, off, 16);
        }
        if (row < nrows) {
            float4 st = make_float4(acc[r][0], acc[r][1], acc[r][2], acc[r][3]);
            *reinterpret_cast<float4*>(&C[(size_t)row * 256 + col0 + tn * 4]) = st;
            if (tn == 0) {
                asrc[row * 4 + head] = ps;
                adst[row * 4 + head] = pd;
            }
        }
    }
}

// ---------------- fused edge softmax + aggregation (gather, online softmax) ----------------
// one block (256 threads = H*C channels) per dst node

__global__ void gat_aggregate(const float* __restrict__ h, const float* __restrict__ asrc,
                              const float* __restrict__ adst, const int* __restrict__ rowptr,
                              const int* __restrict__ csr_src, const float* __restrict__ bias,
                              float* __restrict__ out, int do_relu) {
    const int n = blockIdx.x;
    const int t = threadIdx.x;
    const int head = t >> 6;
    const int start = rowptr[n];
    const int end = rowptr[n + 1];
    const float adst_n = adst[n * 4 + head];

    float m = -INFINITY, s = 0.f, acc = 0.f;
    for (int e = start; e < end; ++e) {
        int src = csr_src[e];
        float sc = asrc[src * 4 + head] + adst_n;
        sc = (sc >= 0.f) ? sc : 0.2f * sc;          // leaky relu 0.2
        float nm = fmaxf(m, sc);
        float scale = __expf(m - nm);               // 0 on first iter
        float w = __expf(sc - nm);
        s = s * scale + w;
        acc = acc * scale + w * h[(size_t)src * 256 + t];
        m = nm;
    }
    float r = acc / s + bias[t];
    if (do_relu) r = fmaxf(r, 0.f);
    out[(size_t)n * 256 + t] = r;
}

// ---------------- pooling (batch is sorted) ----------------

// 64 binary searches replace 40000 contended atomics
__global__ void graph_bounds_kernel(const int* __restrict__ batch, int* __restrict__ cnt) {
    int g = threadIdx.x;
    if (g >= N_GRAPH) return;
    int lo = 0, hi = N_NODES;
    while (lo < hi) { int mid = (lo + hi) >> 1; if (batch[mid] < g) lo = mid + 1; else hi = mid; }
    int start = lo;
    lo = 0; hi = N_NODES;
    while (lo < hi) { int mid = (lo + hi) >> 1; if (batch[mid] < g + 1) lo = mid + 1; else hi = mid; }
    cnt[g] = lo - start;
}

__global__ void pool_kernel(const float* __restrict__ h, const int* __restrict__ batch,
                            float* __restrict__ pooled) {
    const int t = threadIdx.x;       // channel
    const int n0 = blockIdx.x * 256;
    if (n0 >= N_NODES) return;
    const int nend = min(n0 + 256, N_NODES);
    float acc = 0.f;
    int cur = batch[n0];
    for (int n = n0; n < nend; ++n) {
        int g = batch[n];
        if (g != cur) {
            atomicAdd(&pooled[cur * 256 + t], acc);
            acc = 0.f;
            cur = g;
        }
        acc += h[(size_t)n * 256 + t];
    }
    atomicAdd(&pooled[cur * 256 + t], acc);
}

// ---------------- MLP head ----------------

__global__ __launch_bounds__(1024)
void mlp1_kernel(const float* __restrict__ pooled, const int* __restrict__ cnt,
                 const float* __restrict__ W, const float* __restrict__ b,
                 float* __restrict__ hidden) {
    __shared__ float row[256];
    const int g = blockIdx.x, t = threadIdx.x;
    if (t < 256) {
        float c = (float)max(cnt[g], 1);
        row[t] = pooled[g * 256 + t] / c;
    }
    __syncthreads();
    float acc = b[t];
    for (int k = 0; k < 256; k++) acc = fmaf(row[k], W[(size_t)k * NHID + t], acc);
    hidden[g * NHID + t] = fmaxf(acc, 0.f);
}

__global__ __launch_bounds__(768)
void mlp2_kernel(const float* __restrict__ hidden, const float* __restrict__ W,
                 const float* __restrict__ b, float* __restrict__ out) {
    __shared__ float row[NHID];
    const int g = blockIdx.x, t = threadIdx.x;
    row[t] = hidden[g * NHID + t];
    if (t < NHID - NOUT) row[NOUT + t] = hidden[g * NHID + NOUT + t];
    __syncthreads();
    float acc = b[t];
    for (int k = 0; k < NHID; k++) acc = fmaf(row[k], W[(size_t)k * NOUT + t], acc);
    out[g * NOUT + t] = acc;
}

// ---------------- launch ----------------

extern "C" void kernel_launch(void* const* d_in, const int* in_sizes, int n_in,
                              void* d_out, int out_size, void* d_ws, size_t ws_size,
                              hipStream_t stream) {
    const float* x  = (const float*)d_in[0];
    const int* ei   = (const int*)d_in[1];
    const int* batch = (const int*)d_in[2];
    const float* W1 = (const float*)d_in[3];
    const float* as1 = (const float*)d_in[4];
    const float* ad1 = (const float*)d_in[5];
    const float* b1 = (const float*)d_in[6];
    const float* W2 = (const float*)d_in[7];
    const float* as2 = (const float*)d_in[8];
    const float* ad2 = (const float*)d_in[9];
    const float* b2 = (const float*)d_in[10];
    const float* W3 = (const float*)d_in[11];
    const float* as3 = (const float*)d_in[12];
    const float* ad3 = (const float*)d_in[13];
    const float* b3 = (const float*)d_in[14];
    const float* Wm1 = (const float*)d_in[15];
    const float* bm1 = (const float*)d_in[16];
    const float* Wm2 = (const float*)d_in[17];
    const float* bm2 = (const float*)d_in[18];
    float* out = (float*)d_out;

    // workspace layout (256B aligned)
    char* base = (char*)d_ws;
    size_t off = 0;
    auto alloc = [&](size_t bytes) { char* p = base + off; off = (off + bytes + 255) & ~(size_t)255; return p; };
    float* bufA   = (float*)alloc((size_t)N_NODES * 256 * 4);
    float* bufB   = (float*)alloc((size_t)N_NODES * 256 * 4);
    float* asrc   = (float*)alloc((size_t)N_NODES * 4 * 4);
    float* adst   = (float*)alloc((size_t)N_NODES * 4 * 4);
    int*   deg    = (int*)alloc((size_t)N_NODES * 4);
    int*   cursor = (int*)alloc((size_t)N_NODES * 4);
    int*   rowptr = (int*)alloc((size_t)(N_NODES + 1) * 4);
    int*   csrsrc = (int*)alloc((size_t)E_TOT * 4);
    float* pooled = (float*)alloc((size_t)N_GRAPH * 256 * 4);
    int*   cnt    = (int*)alloc((size_t)N_GRAPH * 4);
    float* hidden = (float*)alloc((size_t)N_GRAPH * NHID * 4);
    (void)ws_size; (void)n_in; (void)in_sizes; (void)out_size;

    // zero accumulators (captured each replay)
    hipMemsetAsync(deg, 0, (size_t)N_NODES * 4, stream);
    hipMemsetAsync(cursor, 0, (size_t)N_NODES * 4, stream);
    hipMemsetAsync(pooled, 0, (size_t)N_GRAPH * 256 * 4, stream);

    const int eb = (E_TOT + 255) / 256;
    count_deg_kernel<<<eb, 256, 0, stream>>>(ei, deg);
    scan_kernel<<<1, 1024, 0, stream>>>(deg, rowptr);
    fill_csr_kernel<<<eb, 256, 0, stream>>>(ei, rowptr, cursor, csrsrc);

    dim3 ggrid((N_NODES + GBM - 1) / GBM, 256 / GBN);

    // layer 1
    gemm_kernel<<<ggrid, 256, 0, stream>>>(x, W1, bufA, N_NODES, as1, ad1, asrc, adst);
    gat_aggregate<<<N_NODES, 256, 0, stream>>>(bufA, asrc, adst, rowptr, csrsrc, b1, bufB, 1);
    // layer 2
    gemm_kernel<<<ggrid, 256, 0, stream>>>(bufB, W2, bufA, N_NODES, as2, ad2, asrc, adst);
    gat_aggregate<<<N_NODES, 256, 0, stream>>>(bufA, asrc, adst, rowptr, csrsrc, b2, bufB, 1);
    // layer 3
    gemm_kernel<<<ggrid, 256, 0, stream>>>(bufB, W3, bufA, N_NODES, as3, ad3, asrc, adst);
    gat_aggregate<<<N_NODES, 256, 0, stream>>>(bufA, asrc, adst, rowptr, csrsrc, b3, bufB, 0);

    // pool + MLP
    graph_bounds_kernel<<<1, 64, 0, stream>>>(batch, cnt);
    pool_kernel<<<(N_NODES + 255) / 256, 256, 0, stream>>>(bufB, batch, pooled);
    mlp1_kernel<<<N_GRAPH, 1024, 0, stream>>>(pooled, cnt, Wm1, bm1, hidden);
    mlp2_kernel<<<N_GRAPH, NOUT, 0, stream>>>(hidden, Wm2, bm2, out);
}

// Round 3
// 801.382 us; speedup vs baseline: 1.4456x; 1.1960x over previous
//
#include <hip/hip_runtime.h>
#include <hip/hip_bf16.h>
#include <math.h>

#define N_NODES 40000
#define N_EDGES 640000
#define N_GRAPH 64
#define HEADS 4
#define CHAN 64
#define HC 256          // HEADS*CHAN
#define NHID 1024
#define NOUT 768
#define E_TOT (N_EDGES + N_NODES)

typedef __attribute__((ext_vector_type(8))) short bf16x8;
typedef __attribute__((ext_vector_type(4))) float f32x4;

// ---------------- dtype conversion ----------------

__global__ void cast_x_kernel(const float* __restrict__ x, __hip_bfloat16* __restrict__ xb) {
    int i = blockIdx.x * blockDim.x + threadIdx.x;      // handles 4 elems
    float4 v = *reinterpret_cast<const float4*>(&x[(size_t)i * 4]);
    __hip_bfloat16 o[4] = {__float2bfloat16(v.x), __float2bfloat16(v.y),
                           __float2bfloat16(v.z), __float2bfloat16(v.w)};
    *reinterpret_cast<ushort4*>(&xb[(size_t)i * 4]) = *reinterpret_cast<ushort4*>(o);
}

// Wt[n][k] = bf16(W[k][n])  (transposed so GEMM B-fragments are contiguous)
__global__ void conv_wt_kernel(const float* __restrict__ W, __hip_bfloat16* __restrict__ Wt) {
    int k = blockIdx.x, n = threadIdx.x;
    Wt[(size_t)n * 256 + k] = __float2bfloat16(W[(size_t)k * 256 + n]);
}

// ---------------- CSR build ----------------

__global__ void count_deg_kernel(const int* __restrict__ ei, int* __restrict__ deg) {
    int i = blockIdx.x * blockDim.x + threadIdx.x;
    if (i >= E_TOT) return;
    int dst = (i < N_EDGES) ? ei[N_EDGES + i] : (i - N_EDGES);
    atomicAdd(&deg[dst], 1);
}

__global__ __launch_bounds__(1024)
void scan_kernel(const int* __restrict__ deg, int* __restrict__ rowptr) {
    __shared__ int s[1024];
    const int t = threadIdx.x;
    const int chunk = (N_NODES + 1023) / 1024;   // 40
    const int base = t * chunk;
    int sum = 0;
    for (int i = 0; i < chunk; i++) {
        int idx = base + i;
        if (idx < N_NODES) sum += deg[idx];
    }
    s[t] = sum;
    __syncthreads();
    #pragma unroll
    for (int off = 1; off < 1024; off <<= 1) {
        int x = (t >= off) ? s[t - off] : 0;
        __syncthreads();
        s[t] += x;
        __syncthreads();
    }
    int run = (t > 0) ? s[t - 1] : 0;
    for (int i = 0; i < chunk; i++) {
        int idx = base + i;
        if (idx < N_NODES) { rowptr[idx] = run; run += deg[idx]; }
    }
    if (t == 1023) rowptr[N_NODES] = s[1023];
}

__global__ void fill_csr_kernel(const int* __restrict__ ei, const int* __restrict__ rowptr,
                                int* __restrict__ cursor, int* __restrict__ csr_src) {
    int i = blockIdx.x * blockDim.x + threadIdx.x;
    if (i >= E_TOT) return;
    int src, dst;
    if (i < N_EDGES) { src = ei[i]; dst = ei[N_EDGES + i]; }
    else             { src = dst = i - N_EDGES; }
    int pos = atomicAdd(&cursor[dst], 1);
    csr_src[rowptr[dst] + pos] = src;
}

// ---------------- bf16 MFMA GEMM + fused alpha epilogue ----------------
// C[n,m] = sum_k A[n,k] * W[k,m]; A bf16 [M][256], Wt bf16 [256(n)][256(k)], C bf16.
// 128x128 tile, 4 waves 2x2, each wave 64x64 = 4x4 frags of 16x16x32.

#define GBM 128
#define GBN 128
#define GBK 32

__global__ __launch_bounds__(256)
void gemm_mfma_kernel(const __hip_bfloat16* __restrict__ A, const __hip_bfloat16* __restrict__ Wt,
                      __hip_bfloat16* __restrict__ C, int nrows,
                      const float* __restrict__ a_s, const float* __restrict__ a_d,
                      float* __restrict__ asrc, float* __restrict__ adst) {
    __shared__ ushort A_lds[128][40];   // [row][k], pad 32->40 keeps 16B align, ~2-way banks
    __shared__ ushort B_lds[128][40];   // [col][k]
    const int tid = threadIdx.x;
    const int lane = tid & 63;
    const int l15 = lane & 15;
    const int lq  = lane >> 4;
    const int wid = tid >> 6;
    const int wrow = (wid >> 1) * 64;
    const int wcol = (wid & 1) * 64;
    const int row0 = blockIdx.x * GBM;
    const int col0 = blockIdx.y * GBN;

    f32x4 acc[4][4];
    #pragma unroll
    for (int m = 0; m < 4; m++)
        #pragma unroll
        for (int n = 0; n < 4; n++)
            acc[m][n] = (f32x4){0.f, 0.f, 0.f, 0.f};

    const char* Ab = (const char*)A;
    const char* Wb = (const char*)Wt;

    for (int kt = 0; kt < 256; kt += GBK) {
        __syncthreads();   // previous iter's reads complete before restage
        #pragma unroll
        for (int i = 0; i < 2; i++) {
            int ch = tid + i * 256;
            int r = ch >> 2, sl = ch & 3;
            int arow = row0 + r; if (arow >= nrows) arow = nrows - 1;
            uint4 va = *reinterpret_cast<const uint4*>(Ab + (size_t)arow * 512 + kt * 2 + sl * 16);
            *reinterpret_cast<uint4*>(&A_lds[r][sl * 8]) = va;
            uint4 vb = *reinterpret_cast<const uint4*>(Wb + (size_t)(col0 + r) * 512 + kt * 2 + sl * 16);
            *reinterpret_cast<uint4*>(&B_lds[r][sl * 8]) = vb;
        }
        __syncthreads();
        bf16x8 af[4], bfr[4];
        #pragma unroll
        for (int m = 0; m < 4; m++)
            af[m] = *reinterpret_cast<const bf16x8*>(&A_lds[wrow + m * 16 + l15][lq * 8]);
        #pragma unroll
        for (int n = 0; n < 4; n++)
            bfr[n] = *reinterpret_cast<const bf16x8*>(&B_lds[wcol + n * 16 + l15][lq * 8]);
        #pragma unroll
        for (int m = 0; m < 4; m++)
            #pragma unroll
            for (int n = 0; n < 4; n++)
                acc[m][n] = __builtin_amdgcn_mfma_f32_16x16x32_bf16(af[m], bfr[n], acc[m][n], 0, 0, 0);
    }

    // epilogue: C store (bf16) + fused per-row attention scalars for this wave's head
    const int head = (col0 + wcol) >> 6;    // wave's 64 cols == one head
    float was[4], wad[4];
    #pragma unroll
    for (int n = 0; n < 4; n++) {
        was[n] = a_s[head * 64 + n * 16 + l15];
        wad[n] = a_d[head * 64 + n * 16 + l15];
    }
    #pragma unroll
    for (int m = 0; m < 4; m++) {
        #pragma unroll
        for (int reg = 0; reg < 4; reg++) {
            float ps = 0.f, pd = 0.f;
            #pragma unroll
            for (int n = 0; n < 4; n++) {
                float v = acc[m][n][reg];
                ps = fmaf(v, was[n], ps);
                pd = fmaf(v, wad[n], pd);
            }
            #pragma unroll
            for (int off = 1; off < 16; off <<= 1) {
                ps += __shfl_xor(ps, off, 16);
                pd += __shfl_xor(pd, off, 16);
            }
            int row = row0 + wrow + m * 16 + lq * 4 + reg;
            if (l15 == 0 && row < nrows) {
                asrc[row * 4 + head] = ps;
                adst[row * 4 + head] = pd;
            }
        }
        #pragma unroll
        for (int n = 0; n < 4; n++) {
            int col = col0 + wcol + n * 16 + l15;
            #pragma unroll
            for (int reg = 0; reg < 4; reg++) {
                int row = row0 + wrow + m * 16 + lq * 4 + reg;
                if (row < nrows)
                    C[(size_t)row * 256 + col] = __float2bfloat16(acc[m][n][reg]);
            }
        }
    }
}

// ---------------- edge softmax: normalized weights per (edge, head) ----------------
// one wave per dst node; lane = (edge_sub<<2) | head; 3 passes (max, sum, store)

__global__ __launch_bounds__(256)
void edge_softmax_kernel(const float* __restrict__ asrc, const float* __restrict__ adst,
                         const int* __restrict__ rowptr, const int* __restrict__ csr_src,
                         float* __restrict__ wbuf) {
    const int n = blockIdx.x * 4 + (threadIdx.x >> 6);
    const int lane = threadIdx.x & 63;
    const int h = lane & 3;
    const int sub = lane >> 2;
    const int start = rowptr[n], end = rowptr[n + 1];
    const float ad = adst[n * 4 + h];

    float m = -1e30f;
    for (int base = start; base < end; base += 16) {
        int e = base + sub;
        if (e < end) {
            float sc = asrc[csr_src[e] * 4 + h] + ad;
            sc = (sc >= 0.f) ? sc : 0.2f * sc;
            m = fmaxf(m, sc);
        }
    }
    #pragma unroll
    for (int off = 4; off < 64; off <<= 1) m = fmaxf(m, __shfl_xor(m, off, 64));

    float s = 0.f;
    for (int base = start; base < end; base += 16) {
        int e = base + sub;
        if (e < end) {
            float sc = asrc[csr_src[e] * 4 + h] + ad;
            sc = (sc >= 0.f) ? sc : 0.2f * sc;
            s += __expf(sc - m);
        }
    }
    #pragma unroll
    for (int off = 4; off < 64; off <<= 1) s += __shfl_xor(s, off, 64);
    const float inv = 1.0f / s;

    for (int base = start; base < end; base += 16) {
        int e = base + sub;
        if (e < end) {
            float sc = asrc[csr_src[e] * 4 + h] + ad;
            sc = (sc >= 0.f) ? sc : 0.2f * sc;
            wbuf[(size_t)e * 4 + h] = __expf(sc - m) * inv;
        }
    }
}

// ---------------- aggregation: out[n] = sum_e alpha[e] * h[src[e]] ----------------
// one block (256 threads = H*C channels) per dst node

__global__ __launch_bounds__(256)
void gat_aggregate(const __hip_bfloat16* __restrict__ h, const float* __restrict__ wbuf,
                   const int* __restrict__ rowptr, const int* __restrict__ csr_src,
                   const float* __restrict__ bias, __hip_bfloat16* __restrict__ out, int do_relu) {
    const int n = blockIdx.x;
    const int t = threadIdx.x;
    const int head = t >> 6;
    const int start = rowptr[n], end = rowptr[n + 1];
    float acc = 0.f;
    for (int e = start; e < end; ++e) {
        int src = csr_src[e];
        float w = wbuf[(size_t)e * 4 + head];
        acc = fmaf(w, __bfloat162float(h[(size_t)src * 256 + t]), acc);
    }
    float r = acc + bias[t];
    if (do_relu) r = fmaxf(r, 0.f);
    out[(size_t)n * 256 + t] = __float2bfloat16(r);
}

// ---------------- pooling (batch sorted) ----------------

__global__ void graph_bounds_kernel(const int* __restrict__ batch, int* __restrict__ cnt) {
    int g = threadIdx.x;
    if (g >= N_GRAPH) return;
    int lo = 0, hi = N_NODES;
    while (lo < hi) { int mid = (lo + hi) >> 1; if (batch[mid] < g) lo = mid + 1; else hi = mid; }
    int start = lo;
    lo = 0; hi = N_NODES;
    while (lo < hi) { int mid = (lo + hi) >> 1; if (batch[mid] < g + 1) lo = mid + 1; else hi = mid; }
    cnt[g] = lo - start;
}

__global__ void pool_kernel(const __hip_bfloat16* __restrict__ h, const int* __restrict__ batch,
                            float* __restrict__ pooled) {
    const int t = threadIdx.x;
    const int n0 = blockIdx.x * 256;
    if (n0 >= N_NODES) return;
    const int nend = min(n0 + 256, N_NODES);
    float acc = 0.f;
    int cur = batch[n0];
    for (int n = n0; n < nend; ++n) {
        int g = batch[n];
        if (g != cur) {
            atomicAdd(&pooled[cur * 256 + t], acc);
            acc = 0.f;
            cur = g;
        }
        acc += __bfloat162float(h[(size_t)n * 256 + t]);
    }
    atomicAdd(&pooled[cur * 256 + t], acc);
}

// ---------------- MLP head ----------------

__global__ __launch_bounds__(1024)
void mlp1_kernel(const float* __restrict__ pooled, const int* __restrict__ cnt,
                 const float* __restrict__ W, const float* __restrict__ b,
                 float* __restrict__ hidden) {
    __shared__ float row[256];
    const int g = blockIdx.x, t = threadIdx.x;
    if (t < 256) {
        float c = (float)max(cnt[g], 1);
        row[t] = pooled[g * 256 + t] / c;
    }
    __syncthreads();
    float acc = b[t];
    for (int k = 0; k < 256; k++) acc = fmaf(row[k], W[(size_t)k * NHID + t], acc);
    hidden[g * NHID + t] = fmaxf(acc, 0.f);
}

__global__ __launch_bounds__(768)
void mlp2_kernel(const float* __restrict__ hidden, const float* __restrict__ W,
                 const float* __restrict__ b, float* __restrict__ out) {
    __shared__ float row[NHID];
    const int g = blockIdx.x, t = threadIdx.x;
    row[t] = hidden[g * NHID + t];
    if (t < NHID - NOUT) row[NOUT + t] = hidden[g * NHID + NOUT + t];
    __syncthreads();
    float acc = b[t];
    for (int k = 0; k < NHID; k++) acc = fmaf(row[k], W[(size_t)k * NOUT + t], acc);
    out[g * NOUT + t] = acc;
}

// ---------------- launch ----------------

extern "C" void kernel_launch(void* const* d_in, const int* in_sizes, int n_in,
                              void* d_out, int out_size, void* d_ws, size_t ws_size,
                              hipStream_t stream) {
    const float* x  = (const float*)d_in[0];
    const int* ei   = (const int*)d_in[1];
    const int* batch = (const int*)d_in[2];
    const float* W1 = (const float*)d_in[3];
    const float* as1 = (const float*)d_in[4];
    const float* ad1 = (const float*)d_in[5];
    const float* b1 = (const float*)d_in[6];
    const float* W2 = (const float*)d_in[7];
    const float* as2 = (const float*)d_in[8];
    const float* ad2 = (const float*)d_in[9];
    const float* b2 = (const float*)d_in[10];
    const float* W3 = (const float*)d_in[11];
    const float* as3 = (const float*)d_in[12];
    const float* ad3 = (const float*)d_in[13];
    const float* b3 = (const float*)d_in[14];
    const float* Wm1 = (const float*)d_in[15];
    const float* bm1 = (const float*)d_in[16];
    const float* Wm2 = (const float*)d_in[17];
    const float* bm2 = (const float*)d_in[18];
    float* out = (float*)d_out;

    char* base = (char*)d_ws;
    size_t off = 0;
    auto alloc = [&](size_t bytes) { char* p = base + off; off = (off + bytes + 255) & ~(size_t)255; return p; };
    __hip_bfloat16* x_bf = (__hip_bfloat16*)alloc((size_t)N_NODES * 256 * 2);
    __hip_bfloat16* hA   = (__hip_bfloat16*)alloc((size_t)N_NODES * 256 * 2);
    __hip_bfloat16* hB   = (__hip_bfloat16*)alloc((size_t)N_NODES * 256 * 2);
    __hip_bfloat16* Wt1  = (__hip_bfloat16*)alloc((size_t)256 * 256 * 2);
    __hip_bfloat16* Wt2  = (__hip_bfloat16*)alloc((size_t)256 * 256 * 2);
    __hip_bfloat16* Wt3  = (__hip_bfloat16*)alloc((size_t)256 * 256 * 2);
    float* wbuf   = (float*)alloc((size_t)E_TOT * 4 * 4);
    float* asrc   = (float*)alloc((size_t)N_NODES * 4 * 4);
    float* adst   = (float*)alloc((size_t)N_NODES * 4 * 4);
    int*   deg    = (int*)alloc((size_t)N_NODES * 4);
    int*   cursor = (int*)alloc((size_t)N_NODES * 4);
    int*   rowptr = (int*)alloc((size_t)(N_NODES + 1) * 4);
    int*   csrsrc = (int*)alloc((size_t)E_TOT * 4);
    float* pooled = (float*)alloc((size_t)N_GRAPH * 256 * 4);
    int*   cnt    = (int*)alloc((size_t)N_GRAPH * 4);
    float* hidden = (float*)alloc((size_t)N_GRAPH * NHID * 4);
    (void)ws_size; (void)n_in; (void)in_sizes; (void)out_size;

    hipMemsetAsync(deg, 0, (size_t)N_NODES * 4, stream);
    hipMemsetAsync(cursor, 0, (size_t)N_NODES * 4, stream);
    hipMemsetAsync(pooled, 0, (size_t)N_GRAPH * 256 * 4, stream);

    // dtype prep
    cast_x_kernel<<<(N_NODES * 256 / 4 + 255) / 256, 256, 0, stream>>>(x, x_bf);
    conv_wt_kernel<<<256, 256, 0, stream>>>(W1, Wt1);
    conv_wt_kernel<<<256, 256, 0, stream>>>(W2, Wt2);
    conv_wt_kernel<<<256, 256, 0, stream>>>(W3, Wt3);

    // CSR
    const int eb = (E_TOT + 255) / 256;
    count_deg_kernel<<<eb, 256, 0, stream>>>(ei, deg);
    scan_kernel<<<1, 1024, 0, stream>>>(deg, rowptr);
    fill_csr_kernel<<<eb, 256, 0, stream>>>(ei, rowptr, cursor, csrsrc);

    dim3 ggrid((N_NODES + GBM - 1) / GBM, 256 / GBN);

    // layer 1
    gemm_mfma_kernel<<<ggrid, 256, 0, stream>>>(x_bf, Wt1, hA, N_NODES, as1, ad1, asrc, adst);
    edge_softmax_kernel<<<N_NODES / 4, 256, 0, stream>>>(asrc, adst, rowptr, csrsrc, wbuf);
    gat_aggregate<<<N_NODES, 256, 0, stream>>>(hA, wbuf, rowptr, csrsrc, b1, hB, 1);
    // layer 2
    gemm_mfma_kernel<<<ggrid, 256, 0, stream>>>(hB, Wt2, hA, N_NODES, as2, ad2, asrc, adst);
    edge_softmax_kernel<<<N_NODES / 4, 256, 0, stream>>>(asrc, adst, rowptr, csrsrc, wbuf);
    gat_aggregate<<<N_NODES, 256, 0, stream>>>(hA, wbuf, rowptr, csrsrc, b2, hB, 1);
    // layer 3
    gemm_mfma_kernel<<<ggrid, 256, 0, stream>>>(hB, Wt3, hA, N_NODES, as3, ad3, asrc, adst);
    edge_softmax_kernel<<<N_NODES / 4, 256, 0, stream>>>(asrc, adst, rowptr, csrsrc, wbuf);
    gat_aggregate<<<N_NODES, 256, 0, stream>>>(hA, wbuf, rowptr, csrsrc, b3, hB, 0);

    // pool + MLP
    graph_bounds_kernel<<<1, 64, 0, stream>>>(batch, cnt);
    pool_kernel<<<(N_NODES + 255) / 256, 256, 0, stream>>>(hB, batch, pooled);
    mlp1_kernel<<<N_GRAPH, 1024, 0, stream>>>(pooled, cnt, Wm1, bm1, hidden);
    mlp2_kernel<<<N_GRAPH, NOUT, 0, stream>>>(hidden, Wm2, bm2, out);
}

// Round 4
// 644.478 us; speedup vs baseline: 1.7976x; 1.2435x over previous
//
#include <hip/hip_runtime.h>
#include <hip/hip_bf16.h>
#include <math.h>

#define N_NODES 40000
#define N_EDGES 640000
#define N_GRAPH 64
#define HEADS 4
#define CHAN 64
#define HC 256          // HEADS*CHAN
#define NHID 1024
#define NOUT 768
#define E_TOT (N_EDGES + N_NODES)

typedef __attribute__((ext_vector_type(8))) short bf16x8;
typedef __attribute__((ext_vector_type(4))) float f32x4;

// ---------------- dtype conversion ----------------

__global__ void cast_x_kernel(const float* __restrict__ x, __hip_bfloat16* __restrict__ xb) {
    int i = blockIdx.x * blockDim.x + threadIdx.x;      // handles 4 elems
    float4 v = *reinterpret_cast<const float4*>(&x[(size_t)i * 4]);
    __hip_bfloat16 o[4] = {__float2bfloat16(v.x), __float2bfloat16(v.y),
                           __float2bfloat16(v.z), __float2bfloat16(v.w)};
    *reinterpret_cast<ushort4*>(&xb[(size_t)i * 4]) = *reinterpret_cast<ushort4*>(o);
}

// Wt[n][k] = bf16(W[k][n])  (transposed so GEMM B-fragments are contiguous)
__global__ void conv_wt_kernel(const float* __restrict__ W, __hip_bfloat16* __restrict__ Wt) {
    int k = blockIdx.x, n = threadIdx.x;
    Wt[(size_t)n * 256 + k] = __float2bfloat16(W[(size_t)k * 256 + n]);
}

// ---------------- CSR build ----------------

__global__ void count_deg_kernel(const int* __restrict__ ei, int* __restrict__ deg) {
    int i = blockIdx.x * blockDim.x + threadIdx.x;
    if (i >= E_TOT) return;
    int dst = (i < N_EDGES) ? ei[N_EDGES + i] : (i - N_EDGES);
    atomicAdd(&deg[dst], 1);
}

__global__ __launch_bounds__(1024)
void scan_kernel(const int* __restrict__ deg, int* __restrict__ rowptr) {
    __shared__ int s[1024];
    const int t = threadIdx.x;
    const int chunk = (N_NODES + 1023) / 1024;   // 40
    const int base = t * chunk;
    int sum = 0;
    for (int i = 0; i < chunk; i++) {
        int idx = base + i;
        if (idx < N_NODES) sum += deg[idx];
    }
    s[t] = sum;
    __syncthreads();
    #pragma unroll
    for (int off = 1; off < 1024; off <<= 1) {
        int x = (t >= off) ? s[t - off] : 0;
        __syncthreads();
        s[t] += x;
        __syncthreads();
    }
    int run = (t > 0) ? s[t - 1] : 0;
    for (int i = 0; i < chunk; i++) {
        int idx = base + i;
        if (idx < N_NODES) { rowptr[idx] = run; run += deg[idx]; }
    }
    if (t == 1023) rowptr[N_NODES] = s[1023];
}

__global__ void fill_csr_kernel(const int* __restrict__ ei, const int* __restrict__ rowptr,
                                int* __restrict__ cursor, int* __restrict__ csr_src) {
    int i = blockIdx.x * blockDim.x + threadIdx.x;
    if (i >= E_TOT) return;
    int src, dst;
    if (i < N_EDGES) { src = ei[i]; dst = ei[N_EDGES + i]; }
    else             { src = dst = i - N_EDGES; }
    int pos = atomicAdd(&cursor[dst], 1);
    csr_src[rowptr[dst] + pos] = src;
}

// ---------------- bf16 MFMA GEMM + fused alpha epilogue ----------------

#define GBM 128
#define GBN 128
#define GBK 32

__global__ __launch_bounds__(256)
void gemm_mfma_kernel(const __hip_bfloat16* __restrict__ A, const __hip_bfloat16* __restrict__ Wt,
                      __hip_bfloat16* __restrict__ C, int nrows,
                      const float* __restrict__ a_s, const float* __restrict__ a_d,
                      float* __restrict__ asrc, float* __restrict__ adst) {
    __shared__ ushort A_lds[128][40];   // [row][k], pad 32->40 keeps 16B align
    __shared__ ushort B_lds[128][40];   // [col][k]
    const int tid = threadIdx.x;
    const int lane = tid & 63;
    const int l15 = lane & 15;
    const int lq  = lane >> 4;
    const int wid = tid >> 6;
    const int wrow = (wid >> 1) * 64;
    const int wcol = (wid & 1) * 64;
    const int row0 = blockIdx.x * GBM;
    const int col0 = blockIdx.y * GBN;

    f32x4 acc[4][4];
    #pragma unroll
    for (int m = 0; m < 4; m++)
        #pragma unroll
        for (int n = 0; n < 4; n++)
            acc[m][n] = (f32x4){0.f, 0.f, 0.f, 0.f};

    const char* Ab = (const char*)A;
    const char* Wb = (const char*)Wt;

    for (int kt = 0; kt < 256; kt += GBK) {
        __syncthreads();
        #pragma unroll
        for (int i = 0; i < 2; i++) {
            int ch = tid + i * 256;
            int r = ch >> 2, sl = ch & 3;
            int arow = row0 + r; if (arow >= nrows) arow = nrows - 1;
            uint4 va = *reinterpret_cast<const uint4*>(Ab + (size_t)arow * 512 + kt * 2 + sl * 16);
            *reinterpret_cast<uint4*>(&A_lds[r][sl * 8]) = va;
            uint4 vb = *reinterpret_cast<const uint4*>(Wb + (size_t)(col0 + r) * 512 + kt * 2 + sl * 16);
            *reinterpret_cast<uint4*>(&B_lds[r][sl * 8]) = vb;
        }
        __syncthreads();
        bf16x8 af[4], bfr[4];
        #pragma unroll
        for (int m = 0; m < 4; m++)
            af[m] = *reinterpret_cast<const bf16x8*>(&A_lds[wrow + m * 16 + l15][lq * 8]);
        #pragma unroll
        for (int n = 0; n < 4; n++)
            bfr[n] = *reinterpret_cast<const bf16x8*>(&B_lds[wcol + n * 16 + l15][lq * 8]);
        #pragma unroll
        for (int m = 0; m < 4; m++)
            #pragma unroll
            for (int n = 0; n < 4; n++)
                acc[m][n] = __builtin_amdgcn_mfma_f32_16x16x32_bf16(af[m], bfr[n], acc[m][n], 0, 0, 0);
    }

    const int head = (col0 + wcol) >> 6;
    float was[4], wad[4];
    #pragma unroll
    for (int n = 0; n < 4; n++) {
        was[n] = a_s[head * 64 + n * 16 + l15];
        wad[n] = a_d[head * 64 + n * 16 + l15];
    }
    #pragma unroll
    for (int m = 0; m < 4; m++) {
        #pragma unroll
        for (int reg = 0; reg < 4; reg++) {
            float ps = 0.f, pd = 0.f;
            #pragma unroll
            for (int n = 0; n < 4; n++) {
                float v = acc[m][n][reg];
                ps = fmaf(v, was[n], ps);
                pd = fmaf(v, wad[n], pd);
            }
            #pragma unroll
            for (int off = 1; off < 16; off <<= 1) {
                ps += __shfl_xor(ps, off, 16);
                pd += __shfl_xor(pd, off, 16);
            }
            int row = row0 + wrow + m * 16 + lq * 4 + reg;
            if (l15 == 0 && row < nrows) {
                asrc[row * 4 + head] = ps;
                adst[row * 4 + head] = pd;
            }
        }
        #pragma unroll
        for (int n = 0; n < 4; n++) {
            int col = col0 + wcol + n * 16 + l15;
            #pragma unroll
            for (int reg = 0; reg < 4; reg++) {
                int row = row0 + wrow + m * 16 + lq * 4 + reg;
                if (row < nrows)
                    C[(size_t)row * 256 + col] = __float2bfloat16(acc[m][n][reg]);
            }
        }
    }
}

// ---------------- fused edge-softmax + aggregation, LDS-staged, chunked ----------------
// one block (256 thr) per dst node; chunk of up to 256 edges staged in LDS.
// phases 0-2 use (h4 = t&3, sub = t>>2); phase 3 uses (head = t>>6, channel = t).

#define ACHUNK 256

__global__ __launch_bounds__(256)
void gat_fused_agg(const __hip_bfloat16* __restrict__ h, const float* __restrict__ asrc,
                   const float* __restrict__ adst, const int* __restrict__ rowptr,
                   const int* __restrict__ csr_src, const float* __restrict__ bias,
                   __hip_bfloat16* __restrict__ out, int do_relu) {
    __shared__ int   s_src[ACHUNK];
    __shared__ float s_w[ACHUNK][4];
    __shared__ float s_red[64][4];
    __shared__ float s_state[4][3];     // per head: {m_run, s_run, chunk_scale}

    const int n = blockIdx.x;
    const int t = threadIdx.x;
    const int h4 = t & 3, sub = t >> 2;
    const int head = t >> 6;
    const int start = rowptr[n];
    const int deg = rowptr[n + 1] - start;
    const float ad = adst[n * 4 + h4];
    float acc = 0.f;

    if (t < 4) { s_state[t][0] = -1e30f; s_state[t][1] = 0.f; }

    for (int c0 = 0; c0 < deg; c0 += ACHUNK) {
        const int cn = min(ACHUNK, deg - c0);
        __syncthreads();    // protects s_src/s_w reuse and s_state init
        // ---- phase 0: gather src indices + attention scores into LDS
        float pm = -1e30f;
        for (int e = sub; e < cn; e += 64) {
            int src = csr_src[start + c0 + e];
            if (h4 == 0) s_src[e] = src;
            float sc = asrc[src * 4 + h4] + ad;
            sc = (sc >= 0.f) ? sc : 0.2f * sc;   // leaky relu 0.2
            s_w[e][h4] = sc;
            pm = fmaxf(pm, sc);
        }
        // ---- phase 1: per-head chunk max (tree reduce over sub)
        s_red[sub][h4] = pm;
        #pragma unroll
        for (int off = 32; off >= 1; off >>= 1) {
            __syncthreads();
            if (sub < off) s_red[sub][h4] = fmaxf(s_red[sub][h4], s_red[sub + off][h4]);
        }
        __syncthreads();
        if (t < 4) {
            float m_old = s_state[t][0];
            float m_new = fmaxf(m_old, s_red[0][t]);
            float scale = (m_old < -1e29f) ? 0.f : __expf(m_old - m_new);
            s_state[t][0] = m_new;
            s_state[t][2] = scale;
            s_state[t][1] *= scale;
        }
        __syncthreads();
        // ---- phase 2: exp + per-head chunk sum
        const float m_new = s_state[h4][0];
        float ps = 0.f;
        for (int e = sub; e < cn; e += 64) {
            float w = __expf(s_w[e][h4] - m_new);
            s_w[e][h4] = w;
            ps += w;
        }
        s_red[sub][h4] = ps;
        #pragma unroll
        for (int off = 32; off >= 1; off >>= 1) {
            __syncthreads();
            if (sub < off) s_red[sub][h4] += s_red[sub + off][h4];
        }
        __syncthreads();
        if (t < 4) s_state[t][1] += s_red[0][t];
        __syncthreads();
        // ---- phase 3: gather-accumulate (src from LDS broadcast -> no index dep chain)
        acc *= s_state[head][2];
        #pragma unroll 4
        for (int e = 0; e < cn; e++) {
            acc = fmaf(s_w[e][head], __bfloat162float(h[(size_t)s_src[e] * 256 + t]), acc);
        }
    }
    __syncthreads();
    float r = acc / s_state[head][1] + bias[t];
    if (do_relu) r = fmaxf(r, 0.f);
    out[(size_t)n * 256 + t] = __float2bfloat16(r);
}

// ---------------- pooling (batch sorted) ----------------

__global__ void graph_bounds_kernel(const int* __restrict__ batch, int* __restrict__ cnt) {
    int g = threadIdx.x;
    if (g >= N_GRAPH) return;
    int lo = 0, hi = N_NODES;
    while (lo < hi) { int mid = (lo + hi) >> 1; if (batch[mid] < g) lo = mid + 1; else hi = mid; }
    int start = lo;
    lo = 0; hi = N_NODES;
    while (lo < hi) { int mid = (lo + hi) >> 1; if (batch[mid] < g + 1) lo = mid + 1; else hi = mid; }
    cnt[g] = lo - start;
}

__global__ void pool_kernel(const __hip_bfloat16* __restrict__ h, const int* __restrict__ batch,
                            float* __restrict__ pooled) {
    const int t = threadIdx.x;
    const int n0 = blockIdx.x * 256;
    if (n0 >= N_NODES) return;
    const int nend = min(n0 + 256, N_NODES);
    float acc = 0.f;
    int cur = batch[n0];
    for (int n = n0; n < nend; ++n) {
        int g = batch[n];
        if (g != cur) {
            atomicAdd(&pooled[cur * 256 + t], acc);
            acc = 0.f;
            cur = g;
        }
        acc += __bfloat162float(h[(size_t)n * 256 + t]);
    }
    atomicAdd(&pooled[cur * 256 + t], acc);
}

// ---------------- MLP head ----------------

__global__ __launch_bounds__(1024)
void mlp1_kernel(const float* __restrict__ pooled, const int* __restrict__ cnt,
                 const float* __restrict__ W, const float* __restrict__ b,
                 float* __restrict__ hidden) {
    __shared__ float row[256];
    const int g = blockIdx.x, t = threadIdx.x;
    if (t < 256) {
        float c = (float)max(cnt[g], 1);
        row[t] = pooled[g * 256 + t] / c;
    }
    __syncthreads();
    float acc = b[t];
    for (int k = 0; k < 256; k++) acc = fmaf(row[k], W[(size_t)k * NHID + t], acc);
    hidden[g * NHID + t] = fmaxf(acc, 0.f);
}

__global__ __launch_bounds__(768)
void mlp2_kernel(const float* __restrict__ hidden, const float* __restrict__ W,
                 const float* __restrict__ b, float* __restrict__ out) {
    __shared__ float row[NHID];
    const int g = blockIdx.x, t = threadIdx.x;
    row[t] = hidden[g * NHID + t];
    if (t < NHID - NOUT) row[NOUT + t] = hidden[g * NHID + NOUT + t];
    __syncthreads();
    float acc = b[t];
    for (int k = 0; k < NHID; k++) acc = fmaf(row[k], W[(size_t)k * NOUT + t], acc);
    out[g * NOUT + t] = acc;
}

// ---------------- launch ----------------

extern "C" void kernel_launch(void* const* d_in, const int* in_sizes, int n_in,
                              void* d_out, int out_size, void* d_ws, size_t ws_size,
                              hipStream_t stream) {
    const float* x  = (const float*)d_in[0];
    const int* ei   = (const int*)d_in[1];
    const int* batch = (const int*)d_in[2];
    const float* W1 = (const float*)d_in[3];
    const float* as1 = (const float*)d_in[4];
    const float* ad1 = (const float*)d_in[5];
    const float* b1 = (const float*)d_in[6];
    const float* W2 = (const float*)d_in[7];
    const float* as2 = (const float*)d_in[8];
    const float* ad2 = (const float*)d_in[9];
    const float* b2 = (const float*)d_in[10];
    const float* W3 = (const float*)d_in[11];
    const float* as3 = (const float*)d_in[12];
    const float* ad3 = (const float*)d_in[13];
    const float* b3 = (const float*)d_in[14];
    const float* Wm1 = (const float*)d_in[15];
    const float* bm1 = (const float*)d_in[16];
    const float* Wm2 = (const float*)d_in[17];
    const float* bm2 = (const float*)d_in[18];
    float* out = (float*)d_out;

    char* base = (char*)d_ws;
    size_t off = 0;
    auto alloc = [&](size_t bytes) { char* p = base + off; off = (off + bytes + 255) & ~(size_t)255; return p; };
    __hip_bfloat16* x_bf = (__hip_bfloat16*)alloc((size_t)N_NODES * 256 * 2);
    __hip_bfloat16* hA   = (__hip_bfloat16*)alloc((size_t)N_NODES * 256 * 2);
    __hip_bfloat16* hB   = (__hip_bfloat16*)alloc((size_t)N_NODES * 256 * 2);
    __hip_bfloat16* Wt1  = (__hip_bfloat16*)alloc((size_t)256 * 256 * 2);
    __hip_bfloat16* Wt2  = (__hip_bfloat16*)alloc((size_t)256 * 256 * 2);
    __hip_bfloat16* Wt3  = (__hip_bfloat16*)alloc((size_t)256 * 256 * 2);
    float* asrc   = (float*)alloc((size_t)N_NODES * 4 * 4);
    float* adst   = (float*)alloc((size_t)N_NODES * 4 * 4);
    int*   deg    = (int*)alloc((size_t)N_NODES * 4);
    int*   cursor = (int*)alloc((size_t)N_NODES * 4);
    int*   rowptr = (int*)alloc((size_t)(N_NODES + 1) * 4);
    int*   csrsrc = (int*)alloc((size_t)E_TOT * 4);
    float* pooled = (float*)alloc((size_t)N_GRAPH * 256 * 4);
    int*   cnt    = (int*)alloc((size_t)N_GRAPH * 4);
    float* hidden = (float*)alloc((size_t)N_GRAPH * NHID * 4);
    (void)ws_size; (void)n_in; (void)in_sizes; (void)out_size;

    hipMemsetAsync(deg, 0, (size_t)N_NODES * 4, stream);
    hipMemsetAsync(cursor, 0, (size_t)N_NODES * 4, stream);
    hipMemsetAsync(pooled, 0, (size_t)N_GRAPH * 256 * 4, stream);

    // dtype prep
    cast_x_kernel<<<(N_NODES * 256 / 4 + 255) / 256, 256, 0, stream>>>(x, x_bf);
    conv_wt_kernel<<<256, 256, 0, stream>>>(W1, Wt1);
    conv_wt_kernel<<<256, 256, 0, stream>>>(W2, Wt2);
    conv_wt_kernel<<<256, 256, 0, stream>>>(W3, Wt3);

    // CSR
    const int eb = (E_TOT + 255) / 256;
    count_deg_kernel<<<eb, 256, 0, stream>>>(ei, deg);
    scan_kernel<<<1, 1024, 0, stream>>>(deg, rowptr);
    fill_csr_kernel<<<eb, 256, 0, stream>>>(ei, rowptr, cursor, csrsrc);

    dim3 ggrid((N_NODES + GBM - 1) / GBM, 256 / GBN);

    // layer 1
    gemm_mfma_kernel<<<ggrid, 256, 0, stream>>>(x_bf, Wt1, hA, N_NODES, as1, ad1, asrc, adst);
    gat_fused_agg<<<N_NODES, 256, 0, stream>>>(hA, asrc, adst, rowptr, csrsrc, b1, hB, 1);
    // layer 2
    gemm_mfma_kernel<<<ggrid, 256, 0, stream>>>(hB, Wt2, hA, N_NODES, as2, ad2, asrc, adst);
    gat_fused_agg<<<N_NODES, 256, 0, stream>>>(hA, asrc, adst, rowptr, csrsrc, b2, hB, 1);
    // layer 3
    gemm_mfma_kernel<<<ggrid, 256, 0, stream>>>(hB, Wt3, hA, N_NODES, as3, ad3, asrc, adst);
    gat_fused_agg<<<N_NODES, 256, 0, stream>>>(hA, asrc, adst, rowptr, csrsrc, b3, hB, 0);

    // pool + MLP
    graph_bounds_kernel<<<1, 64, 0, stream>>>(batch, cnt);
    pool_kernel<<<(N_NODES + 255) / 256, 256, 0, stream>>>(hB, batch, pooled);
    mlp1_kernel<<<N_GRAPH, 1024, 0, stream>>>(pooled, cnt, Wm1, bm1, hidden);
    mlp2_kernel<<<N_GRAPH, NOUT, 0, stream>>>(hidden, Wm2, bm2, out);
}

// Round 5
// 522.164 us; speedup vs baseline: 2.2187x; 1.2342x over previous
//
#include <hip/hip_runtime.h>
#include <hip/hip_bf16.h>
#include <math.h>

#define N_NODES 40000
#define N_EDGES 640000
#define N_GRAPH 64
#define HEADS 4
#define CHAN 64
#define HC 256          // HEADS*CHAN
#define NHID 1024
#define NOUT 768
#define E_TOT (N_EDGES + N_NODES)

typedef __attribute__((ext_vector_type(8))) short bf16x8;
typedef __attribute__((ext_vector_type(4))) float f32x4;

__device__ inline float bflo(unsigned u) { return __uint_as_float(u << 16); }
__device__ inline float bfhi(unsigned u) { return __uint_as_float(u & 0xffff0000u); }

// ---------------- dtype conversion ----------------

__global__ void cast_x_kernel(const float* __restrict__ x, __hip_bfloat16* __restrict__ xb) {
    int i = blockIdx.x * blockDim.x + threadIdx.x;      // handles 4 elems
    float4 v = *reinterpret_cast<const float4*>(&x[(size_t)i * 4]);
    __hip_bfloat16 o[4] = {__float2bfloat16(v.x), __float2bfloat16(v.y),
                           __float2bfloat16(v.z), __float2bfloat16(v.w)};
    *reinterpret_cast<ushort4*>(&xb[(size_t)i * 4]) = *reinterpret_cast<ushort4*>(o);
}

// Wt[n][k] = bf16(W[k][n])  (transposed so GEMM B-fragments are contiguous)
__global__ void conv_wt_kernel(const float* __restrict__ W, __hip_bfloat16* __restrict__ Wt) {
    int k = blockIdx.x, n = threadIdx.x;
    Wt[(size_t)n * 256 + k] = __float2bfloat16(W[(size_t)k * 256 + n]);
}

// ---------------- CSR build ----------------

__global__ void count_deg_kernel(const int* __restrict__ ei, int* __restrict__ deg) {
    int i = blockIdx.x * blockDim.x + threadIdx.x;
    if (i >= E_TOT) return;
    int dst = (i < N_EDGES) ? ei[N_EDGES + i] : (i - N_EDGES);
    atomicAdd(&deg[dst], 1);
}

__global__ __launch_bounds__(1024)
void scan_kernel(const int* __restrict__ deg, int* __restrict__ rowptr) {
    __shared__ int s[1024];
    const int t = threadIdx.x;
    const int chunk = (N_NODES + 1023) / 1024;   // 40
    const int base = t * chunk;
    int sum = 0;
    for (int i = 0; i < chunk; i++) {
        int idx = base + i;
        if (idx < N_NODES) sum += deg[idx];
    }
    s[t] = sum;
    __syncthreads();
    #pragma unroll
    for (int off = 1; off < 1024; off <<= 1) {
        int x = (t >= off) ? s[t - off] : 0;
        __syncthreads();
        s[t] += x;
        __syncthreads();
    }
    int run = (t > 0) ? s[t - 1] : 0;
    for (int i = 0; i < chunk; i++) {
        int idx = base + i;
        if (idx < N_NODES) { rowptr[idx] = run; run += deg[idx]; }
    }
    if (t == 1023) rowptr[N_NODES] = s[1023];
}

__global__ void fill_csr_kernel(const int* __restrict__ ei, const int* __restrict__ rowptr,
                                int* __restrict__ cursor, int* __restrict__ csr_src) {
    int i = blockIdx.x * blockDim.x + threadIdx.x;
    if (i >= E_TOT) return;
    int src, dst;
    if (i < N_EDGES) { src = ei[i]; dst = ei[N_EDGES + i]; }
    else             { src = dst = i - N_EDGES; }
    int pos = atomicAdd(&cursor[dst], 1);
    csr_src[rowptr[dst] + pos] = src;
}

// ---------------- bf16 MFMA GEMM + fused alpha epilogue ----------------

#define GBM 128
#define GBN 128
#define GBK 32

__global__ __launch_bounds__(256)
void gemm_mfma_kernel(const __hip_bfloat16* __restrict__ A, const __hip_bfloat16* __restrict__ Wt,
                      __hip_bfloat16* __restrict__ C, int nrows,
                      const float* __restrict__ a_s, const float* __restrict__ a_d,
                      float* __restrict__ asrc, float* __restrict__ adst) {
    __shared__ ushort A_lds[128][40];   // [row][k], pad 32->40 keeps 16B align
    __shared__ ushort B_lds[128][40];   // [col][k]
    const int tid = threadIdx.x;
    const int lane = tid & 63;
    const int l15 = lane & 15;
    const int lq  = lane >> 4;
    const int wid = tid >> 6;
    const int wrow = (wid >> 1) * 64;
    const int wcol = (wid & 1) * 64;
    const int row0 = blockIdx.x * GBM;
    const int col0 = blockIdx.y * GBN;

    f32x4 acc[4][4];
    #pragma unroll
    for (int m = 0; m < 4; m++)
        #pragma unroll
        for (int n = 0; n < 4; n++)
            acc[m][n] = (f32x4){0.f, 0.f, 0.f, 0.f};

    const char* Ab = (const char*)A;
    const char* Wb = (const char*)Wt;

    for (int kt = 0; kt < 256; kt += GBK) {
        __syncthreads();
        #pragma unroll
        for (int i = 0; i < 2; i++) {
            int ch = tid + i * 256;
            int r = ch >> 2, sl = ch & 3;
            int arow = row0 + r; if (arow >= nrows) arow = nrows - 1;
            uint4 va = *reinterpret_cast<const uint4*>(Ab + (size_t)arow * 512 + kt * 2 + sl * 16);
            *reinterpret_cast<uint4*>(&A_lds[r][sl * 8]) = va;
            uint4 vb = *reinterpret_cast<const uint4*>(Wb + (size_t)(col0 + r) * 512 + kt * 2 + sl * 16);
            *reinterpret_cast<uint4*>(&B_lds[r][sl * 8]) = vb;
        }
        __syncthreads();
        bf16x8 af[4], bfr[4];
        #pragma unroll
        for (int m = 0; m < 4; m++)
            af[m] = *reinterpret_cast<const bf16x8*>(&A_lds[wrow + m * 16 + l15][lq * 8]);
        #pragma unroll
        for (int n = 0; n < 4; n++)
            bfr[n] = *reinterpret_cast<const bf16x8*>(&B_lds[wcol + n * 16 + l15][lq * 8]);
        #pragma unroll
        for (int m = 0; m < 4; m++)
            #pragma unroll
            for (int n = 0; n < 4; n++)
                acc[m][n] = __builtin_amdgcn_mfma_f32_16x16x32_bf16(af[m], bfr[n], acc[m][n], 0, 0, 0);
    }

    const int head = (col0 + wcol) >> 6;
    float was[4], wad[4];
    #pragma unroll
    for (int n = 0; n < 4; n++) {
        was[n] = a_s[head * 64 + n * 16 + l15];
        wad[n] = a_d[head * 64 + n * 16 + l15];
    }
    #pragma unroll
    for (int m = 0; m < 4; m++) {
        #pragma unroll
        for (int reg = 0; reg < 4; reg++) {
            float ps = 0.f, pd = 0.f;
            #pragma unroll
            for (int n = 0; n < 4; n++) {
                float v = acc[m][n][reg];
                ps = fmaf(v, was[n], ps);
                pd = fmaf(v, wad[n], pd);
            }
            #pragma unroll
            for (int off = 1; off < 16; off <<= 1) {
                ps += __shfl_xor(ps, off, 16);
                pd += __shfl_xor(pd, off, 16);
            }
            int row = row0 + wrow + m * 16 + lq * 4 + reg;
            if (l15 == 0 && row < nrows) {
                asrc[row * 4 + head] = ps;
                adst[row * 4 + head] = pd;
            }
        }
        #pragma unroll
        for (int n = 0; n < 4; n++) {
            int col = col0 + wcol + n * 16 + l15;
            #pragma unroll
            for (int reg = 0; reg < 4; reg++) {
                int row = row0 + wrow + m * 16 + lq * 4 + reg;
                if (row < nrows)
                    C[(size_t)row * 256 + col] = __float2bfloat16(acc[m][n][reg]);
            }
        }
    }
}

// ---------------- fused edge-softmax + aggregation (max-free, wave-per-head) ----------------
// one block per dst node. Phase 0: wave w computes exp-weights for head w (no barriers,
// wave-shuffle sum). Phase 1: 8 groups x 32 lanes, group g does edges e%8==g, 8 ch/lane
// via uint4 loads; partials combined through LDS at the end.
// softmax shift-invariance: exp(sc)/sum(exp(sc)) == ref's exp(sc-m)/sum(exp(sc-m)); scores are O(1).

#define ACHUNK 256

__global__ __launch_bounds__(256)
void gat_fused_agg(const __hip_bfloat16* __restrict__ h, const float* __restrict__ asrc,
                   const float* __restrict__ adst, const int* __restrict__ rowptr,
                   const int* __restrict__ csr_src, const float* __restrict__ bias,
                   __hip_bfloat16* __restrict__ out, int do_relu) {
    __shared__ int   s_src[ACHUNK];
    __shared__ float s_w[ACHUNK][5];    // pad 4->5: conflict-free phase-0 writes
    __shared__ float s_acc[8][HC];
    __shared__ float s_sum[4];

    const int n = blockIdx.x;
    const int t = threadIdx.x;
    const int lane = t & 63;
    const int wid = t >> 6;         // wave id == head in phase 0
    const int grp = t >> 5;         // phase-1 group (edge parity)
    const int gl  = t & 31;         // lane in group; channels gl*8..gl*8+7
    const int h3  = gl >> 3;        // head owning those channels
    const int start = rowptr[n];
    const int deg = rowptr[n + 1] - start;
    const float ad = adst[n * 4 + wid];

    float ssum = 0.f;
    float acc[8] = {0.f, 0.f, 0.f, 0.f, 0.f, 0.f, 0.f, 0.f};

    for (int c0 = 0; c0 < deg; c0 += ACHUNK) {
        const int cn = min(ACHUNK, deg - c0);
        if (c0) __syncthreads();            // previous phase-1 reads done before restage
        // phase 0: per-head exp weights (wave-local, no barriers)
        for (int e = lane; e < cn; e += 64) {
            int src = csr_src[start + c0 + e];
            if (wid == 0) s_src[e] = src;
            float sc = asrc[src * 4 + wid] + ad;
            sc = (sc >= 0.f) ? sc : 0.2f * sc;   // leaky relu 0.2
            float w = __expf(sc);
            s_w[e][wid] = w;
            ssum += w;
        }
        __syncthreads();
        // phase 1: widened gather-accumulate; group g -> edges e%8==g, 8 ch/lane
        #pragma unroll 2
        for (int e = grp; e < cn; e += 8) {
            float w = s_w[e][h3];
            uint4 v = *reinterpret_cast<const uint4*>(&h[(size_t)s_src[e] * HC + gl * 8]);
            acc[0] = fmaf(w, bflo(v.x), acc[0]);
            acc[1] = fmaf(w, bfhi(v.x), acc[1]);
            acc[2] = fmaf(w, bflo(v.y), acc[2]);
            acc[3] = fmaf(w, bfhi(v.y), acc[3]);
            acc[4] = fmaf(w, bflo(v.z), acc[4]);
            acc[5] = fmaf(w, bfhi(v.z), acc[5]);
            acc[6] = fmaf(w, bflo(v.w), acc[6]);
            acc[7] = fmaf(w, bfhi(v.w), acc[7]);
        }
    }
    // reduce exp-sums within each wave (head = wid)
    #pragma unroll
    for (int off = 1; off < 64; off <<= 1) ssum += __shfl_xor(ssum, off, 64);
    if (lane == 0) s_sum[wid] = ssum;
    // publish group partials
    #pragma unroll
    for (int j = 0; j < 8; j++) s_acc[grp][gl * 8 + j] = acc[j];
    __syncthreads();
    // final: thread t owns channel t
    float tot = 0.f;
    #pragma unroll
    for (int g = 0; g < 8; g++) tot += s_acc[g][t];
    float r = tot / s_sum[t >> 6] + bias[t];
    if (do_relu) r = fmaxf(r, 0.f);
    out[(size_t)n * HC + t] = __float2bfloat16(r);
}

// ---------------- pooling (batch sorted) ----------------

__global__ void graph_bounds_kernel(const int* __restrict__ batch, int* __restrict__ cnt) {
    int g = threadIdx.x;
    if (g >= N_GRAPH) return;
    int lo = 0, hi = N_NODES;
    while (lo < hi) { int mid = (lo + hi) >> 1; if (batch[mid] < g) lo = mid + 1; else hi = mid; }
    int start = lo;
    lo = 0; hi = N_NODES;
    while (lo < hi) { int mid = (lo + hi) >> 1; if (batch[mid] < g + 1) lo = mid + 1; else hi = mid; }
    cnt[g] = lo - start;
}

__global__ void pool_kernel(const __hip_bfloat16* __restrict__ h, const int* __restrict__ batch,
                            float* __restrict__ pooled) {
    const int t = threadIdx.x;
    const int n0 = blockIdx.x * 256;
    if (n0 >= N_NODES) return;
    const int nend = min(n0 + 256, N_NODES);
    float acc = 0.f;
    int cur = batch[n0];
    for (int n = n0; n < nend; ++n) {
        int g = batch[n];
        if (g != cur) {
            atomicAdd(&pooled[cur * 256 + t], acc);
            acc = 0.f;
            cur = g;
        }
        acc += __bfloat162float(h[(size_t)n * 256 + t]);
    }
    atomicAdd(&pooled[cur * 256 + t], acc);
}

// ---------------- MLP head ----------------

__global__ __launch_bounds__(1024)
void mlp1_kernel(const float* __restrict__ pooled, const int* __restrict__ cnt,
                 const float* __restrict__ W, const float* __restrict__ b,
                 float* __restrict__ hidden) {
    __shared__ float row[256];
    const int g = blockIdx.x, t = threadIdx.x;
    if (t < 256) {
        float c = (float)max(cnt[g], 1);
        row[t] = pooled[g * 256 + t] / c;
    }
    __syncthreads();
    float acc = b[t];
    for (int k = 0; k < 256; k++) acc = fmaf(row[k], W[(size_t)k * NHID + t], acc);
    hidden[g * NHID + t] = fmaxf(acc, 0.f);
}

__global__ __launch_bounds__(768)
void mlp2_kernel(const float* __restrict__ hidden, const float* __restrict__ W,
                 const float* __restrict__ b, float* __restrict__ out) {
    __shared__ float row[NHID];
    const int g = blockIdx.x, t = threadIdx.x;
    row[t] = hidden[g * NHID + t];
    if (t < NHID - NOUT) row[NOUT + t] = hidden[g * NHID + NOUT + t];
    __syncthreads();
    float acc = b[t];
    for (int k = 0; k < NHID; k++) acc = fmaf(row[k], W[(size_t)k * NOUT + t], acc);
    out[g * NOUT + t] = acc;
}

// ---------------- launch ----------------

extern "C" void kernel_launch(void* const* d_in, const int* in_sizes, int n_in,
                              void* d_out, int out_size, void* d_ws, size_t ws_size,
                              hipStream_t stream) {
    const float* x  = (const float*)d_in[0];
    const int* ei   = (const int*)d_in[1];
    const int* batch = (const int*)d_in[2];
    const float* W1 = (const float*)d_in[3];
    const float* as1 = (const float*)d_in[4];
    const float* ad1 = (const float*)d_in[5];
    const float* b1 = (const float*)d_in[6];
    const float* W2 = (const float*)d_in[7];
    const float* as2 = (const float*)d_in[8];
    const float* ad2 = (const float*)d_in[9];
    const float* b2 = (const float*)d_in[10];
    const float* W3 = (const float*)d_in[11];
    const float* as3 = (const float*)d_in[12];
    const float* ad3 = (const float*)d_in[13];
    const float* b3 = (const float*)d_in[14];
    const float* Wm1 = (const float*)d_in[15];
    const float* bm1 = (const float*)d_in[16];
    const float* Wm2 = (const float*)d_in[17];
    const float* bm2 = (const float*)d_in[18];
    float* out = (float*)d_out;

    char* base = (char*)d_ws;
    size_t off = 0;
    auto alloc = [&](size_t bytes) { char* p = base + off; off = (off + bytes + 255) & ~(size_t)255; return p; };
    __hip_bfloat16* x_bf = (__hip_bfloat16*)alloc((size_t)N_NODES * 256 * 2);
    __hip_bfloat16* hA   = (__hip_bfloat16*)alloc((size_t)N_NODES * 256 * 2);
    __hip_bfloat16* hB   = (__hip_bfloat16*)alloc((size_t)N_NODES * 256 * 2);
    __hip_bfloat16* Wt1  = (__hip_bfloat16*)alloc((size_t)256 * 256 * 2);
    __hip_bfloat16* Wt2  = (__hip_bfloat16*)alloc((size_t)256 * 256 * 2);
    __hip_bfloat16* Wt3  = (__hip_bfloat16*)alloc((size_t)256 * 256 * 2);
    float* asrc   = (float*)alloc((size_t)N_NODES * 4 * 4);
    float* adst   = (float*)alloc((size_t)N_NODES * 4 * 4);
    int*   deg    = (int*)alloc((size_t)N_NODES * 4);
    int*   cursor = (int*)alloc((size_t)N_NODES * 4);
    int*   rowptr = (int*)alloc((size_t)(N_NODES + 1) * 4);
    int*   csrsrc = (int*)alloc((size_t)E_TOT * 4);
    float* pooled = (float*)alloc((size_t)N_GRAPH * 256 * 4);
    int*   cnt    = (int*)alloc((size_t)N_GRAPH * 4);
    float* hidden = (float*)alloc((size_t)N_GRAPH * NHID * 4);
    (void)ws_size; (void)n_in; (void)in_sizes; (void)out_size;

    hipMemsetAsync(deg, 0, (size_t)N_NODES * 4, stream);
    hipMemsetAsync(cursor, 0, (size_t)N_NODES * 4, stream);
    hipMemsetAsync(pooled, 0, (size_t)N_GRAPH * 256 * 4, stream);

    // dtype prep
    cast_x_kernel<<<(N_NODES * 256 / 4 + 255) / 256, 256, 0, stream>>>(x, x_bf);
    conv_wt_kernel<<<256, 256, 0, stream>>>(W1, Wt1);
    conv_wt_kernel<<<256, 256, 0, stream>>>(W2, Wt2);
    conv_wt_kernel<<<256, 256, 0, stream>>>(W3, Wt3);

    // CSR
    const int eb = (E_TOT + 255) / 256;
    count_deg_kernel<<<eb, 256, 0, stream>>>(ei, deg);
    scan_kernel<<<1, 1024, 0, stream>>>(deg, rowptr);
    fill_csr_kernel<<<eb, 256, 0, stream>>>(ei, rowptr, cursor, csrsrc);

    dim3 ggrid((N_NODES + GBM - 1) / GBM, 256 / GBN);

    // layer 1
    gemm_mfma_kernel<<<ggrid, 256, 0, stream>>>(x_bf, Wt1, hA, N_NODES, as1, ad1, asrc, adst);
    gat_fused_agg<<<N_NODES, 256, 0, stream>>>(hA, asrc, adst, rowptr, csrsrc, b1, hB, 1);
    // layer 2
    gemm_mfma_kernel<<<ggrid, 256, 0, stream>>>(hB, Wt2, hA, N_NODES, as2, ad2, asrc, adst);
    gat_fused_agg<<<N_NODES, 256, 0, stream>>>(hA, asrc, adst, rowptr, csrsrc, b2, hB, 1);
    // layer 3
    gemm_mfma_kernel<<<ggrid, 256, 0, stream>>>(hB, Wt3, hA, N_NODES, as3, ad3, asrc, adst);
    gat_fused_agg<<<N_NODES, 256, 0, stream>>>(hA, asrc, adst, rowptr, csrsrc, b3, hB, 0);

    // pool + MLP
    graph_bounds_kernel<<<1, 64, 0, stream>>>(batch, cnt);
    pool_kernel<<<(N_NODES + 255) / 256, 256, 0, stream>>>(hB, batch, pooled);
    mlp1_kernel<<<N_GRAPH, 1024, 0, stream>>>(pooled, cnt, Wm1, bm1, hidden);
    mlp2_kernel<<<N_GRAPH, NOUT, 0, stream>>>(hidden, Wm2, bm2, out);
}

// Round 6
// 457.731 us; speedup vs baseline: 2.5310x; 1.1408x over previous
//
#include <hip/hip_runtime.h>
#include <hip/hip_bf16.h>
#include <math.h>

#define N_NODES 40000
#define N_EDGES 640000
#define N_GRAPH 64
#define HEADS 4
#define CHAN 64
#define HC 256          // HEADS*CHAN
#define NHID 1024
#define NOUT 768
#define E_TOT (N_EDGES + N_NODES)
#define SCAN_NB ((N_NODES + 255) / 256)   // 157

typedef __attribute__((ext_vector_type(8))) short bf16x8;
typedef __attribute__((ext_vector_type(4))) float f32x4;

__device__ inline float bflo(unsigned u) { return __uint_as_float(u << 16); }
__device__ inline float bfhi(unsigned u) { return __uint_as_float(u & 0xffff0000u); }

// ---------------- dtype conversion ----------------

__global__ void cast_x_kernel(const float* __restrict__ x, __hip_bfloat16* __restrict__ xb) {
    int i = blockIdx.x * blockDim.x + threadIdx.x;      // handles 4 elems
    float4 v = *reinterpret_cast<const float4*>(&x[(size_t)i * 4]);
    __hip_bfloat16 o[4] = {__float2bfloat16(v.x), __float2bfloat16(v.y),
                           __float2bfloat16(v.z), __float2bfloat16(v.w)};
    *reinterpret_cast<ushort4*>(&xb[(size_t)i * 4]) = *reinterpret_cast<ushort4*>(o);
}

// Wt[n][k] = bf16(W[k][n])  (transposed so GEMM B-fragments are contiguous)
__global__ void conv_wt_kernel(const float* __restrict__ W, __hip_bfloat16* __restrict__ Wt) {
    int k = blockIdx.x, n = threadIdx.x;
    Wt[(size_t)n * 256 + k] = __float2bfloat16(W[(size_t)k * 256 + n]);
}

// ---------------- CSR build ----------------

__global__ void count_deg_kernel(const int* __restrict__ ei, int* __restrict__ deg) {
    int i = blockIdx.x * blockDim.x + threadIdx.x;
    if (i >= E_TOT) return;
    int dst = (i < N_EDGES) ? ei[N_EDGES + i] : (i - N_EDGES);
    atomicAdd(&deg[dst], 1);
}

// ---- multi-block exclusive scan of deg -> rowptr (3 phases) ----

__global__ __launch_bounds__(256)
void scan_p1_kernel(const int* __restrict__ deg, int* __restrict__ bsum) {
    const int b = blockIdx.x, t = threadIdx.x;
    const int i = b * 256 + t;
    int v = (i < N_NODES) ? deg[i] : 0;
    #pragma unroll
    for (int off = 1; off < 64; off <<= 1) v += __shfl_xor(v, off, 64);
    __shared__ int ws[4];
    if ((t & 63) == 0) ws[t >> 6] = v;
    __syncthreads();
    if (t == 0) bsum[b] = ws[0] + ws[1] + ws[2] + ws[3];
}

__global__ __launch_bounds__(256)
void scan_p2_kernel(int* __restrict__ bsum) {     // single block; SCAN_NB <= 256
    __shared__ int s[256];
    const int t = threadIdx.x;
    int v = (t < SCAN_NB) ? bsum[t] : 0;
    s[t] = v;
    __syncthreads();
    #pragma unroll
    for (int off = 1; off < 256; off <<= 1) {
        int x = (t >= off) ? s[t - off] : 0;
        __syncthreads();
        s[t] += x;
        __syncthreads();
    }
    if (t < SCAN_NB) bsum[t] = s[t] - v;          // exclusive block offset
}

__global__ __launch_bounds__(256)
void scan_p3_kernel(const int* __restrict__ deg, const int* __restrict__ bsum,
                    int* __restrict__ rowptr) {
    __shared__ int s[256];
    const int b = blockIdx.x, t = threadIdx.x;
    const int i = b * 256 + t;
    int v = (i < N_NODES) ? deg[i] : 0;
    s[t] = v;
    __syncthreads();
    #pragma unroll
    for (int off = 1; off < 256; off <<= 1) {
        int x = (t >= off) ? s[t - off] : 0;
        __syncthreads();
        s[t] += x;
        __syncthreads();
    }
    if (i < N_NODES) rowptr[i] = bsum[b] + s[t] - v;
    if (i == 0) rowptr[N_NODES] = E_TOT;          // total is static
}

__global__ void fill_csr_kernel(const int* __restrict__ ei, const int* __restrict__ rowptr,
                                int* __restrict__ cursor, int* __restrict__ csr_src) {
    int i = blockIdx.x * blockDim.x + threadIdx.x;
    if (i >= E_TOT) return;
    int src, dst;
    if (i < N_EDGES) { src = ei[i]; dst = ei[N_EDGES + i]; }
    else             { src = dst = i - N_EDGES; }
    int pos = atomicAdd(&cursor[dst], 1);
    csr_src[rowptr[dst] + pos] = src;
}

// ---------------- bf16 MFMA GEMM + fused alpha epilogue ----------------

#define GBM 128
#define GBN 128
#define GBK 32

__global__ __launch_bounds__(256)
void gemm_mfma_kernel(const __hip_bfloat16* __restrict__ A, const __hip_bfloat16* __restrict__ Wt,
                      __hip_bfloat16* __restrict__ C, int nrows,
                      const float* __restrict__ a_s, const float* __restrict__ a_d,
                      float* __restrict__ asrc, float* __restrict__ adst) {
    __shared__ ushort A_lds[128][40];   // [row][k], pad 32->40 keeps 16B align
    __shared__ ushort B_lds[128][40];   // [col][k]
    const int tid = threadIdx.x;
    const int lane = tid & 63;
    const int l15 = lane & 15;
    const int lq  = lane >> 4;
    const int wid = tid >> 6;
    const int wrow = (wid >> 1) * 64;
    const int wcol = (wid & 1) * 64;
    const int row0 = blockIdx.x * GBM;
    const int col0 = blockIdx.y * GBN;

    f32x4 acc[4][4];
    #pragma unroll
    for (int m = 0; m < 4; m++)
        #pragma unroll
        for (int n = 0; n < 4; n++)
            acc[m][n] = (f32x4){0.f, 0.f, 0.f, 0.f};

    const char* Ab = (const char*)A;
    const char* Wb = (const char*)Wt;

    for (int kt = 0; kt < 256; kt += GBK) {
        __syncthreads();
        #pragma unroll
        for (int i = 0; i < 2; i++) {
            int ch = tid + i * 256;
            int r = ch >> 2, sl = ch & 3;
            int arow = row0 + r; if (arow >= nrows) arow = nrows - 1;
            uint4 va = *reinterpret_cast<const uint4*>(Ab + (size_t)arow * 512 + kt * 2 + sl * 16);
            *reinterpret_cast<uint4*>(&A_lds[r][sl * 8]) = va;
            uint4 vb = *reinterpret_cast<const uint4*>(Wb + (size_t)(col0 + r) * 512 + kt * 2 + sl * 16);
            *reinterpret_cast<uint4*>(&B_lds[r][sl * 8]) = vb;
        }
        __syncthreads();
        bf16x8 af[4], bfr[4];
        #pragma unroll
        for (int m = 0; m < 4; m++)
            af[m] = *reinterpret_cast<const bf16x8*>(&A_lds[wrow + m * 16 + l15][lq * 8]);
        #pragma unroll
        for (int n = 0; n < 4; n++)
            bfr[n] = *reinterpret_cast<const bf16x8*>(&B_lds[wcol + n * 16 + l15][lq * 8]);
        #pragma unroll
        for (int m = 0; m < 4; m++)
            #pragma unroll
            for (int n = 0; n < 4; n++)
                acc[m][n] = __builtin_amdgcn_mfma_f32_16x16x32_bf16(af[m], bfr[n], acc[m][n], 0, 0, 0);
    }

    const int head = (col0 + wcol) >> 6;
    float was[4], wad[4];
    #pragma unroll
    for (int n = 0; n < 4; n++) {
        was[n] = a_s[head * 64 + n * 16 + l15];
        wad[n] = a_d[head * 64 + n * 16 + l15];
    }
    #pragma unroll
    for (int m = 0; m < 4; m++) {
        #pragma unroll
        for (int reg = 0; reg < 4; reg++) {
            float ps = 0.f, pd = 0.f;
            #pragma unroll
            for (int n = 0; n < 4; n++) {
                float v = acc[m][n][reg];
                ps = fmaf(v, was[n], ps);
                pd = fmaf(v, wad[n], pd);
            }
            #pragma unroll
            for (int off = 1; off < 16; off <<= 1) {
                ps += __shfl_xor(ps, off, 16);
                pd += __shfl_xor(pd, off, 16);
            }
            int row = row0 + wrow + m * 16 + lq * 4 + reg;
            if (l15 == 0 && row < nrows) {
                asrc[row * 4 + head] = ps;
                adst[row * 4 + head] = pd;
            }
        }
        #pragma unroll
        for (int n = 0; n < 4; n++) {
            int col = col0 + wcol + n * 16 + l15;
            #pragma unroll
            for (int reg = 0; reg < 4; reg++) {
                int row = row0 + wrow + m * 16 + lq * 4 + reg;
                if (row < nrows)
                    C[(size_t)row * 256 + col] = __float2bfloat16(acc[m][n][reg]);
            }
        }
    }
}

// ---------------- fused edge-softmax + aggregation (max-free, wave-per-head) ----------------

#define ACHUNK 256

__global__ __launch_bounds__(256)
void gat_fused_agg(const __hip_bfloat16* __restrict__ h, const float* __restrict__ asrc,
                   const float* __restrict__ adst, const int* __restrict__ rowptr,
                   const int* __restrict__ csr_src, const float* __restrict__ bias,
                   __hip_bfloat16* __restrict__ out, int do_relu) {
    __shared__ int   s_src[ACHUNK];
    __shared__ float s_w[ACHUNK][5];    // pad 4->5: conflict-free phase-0 writes
    __shared__ float s_acc[8][HC];
    __shared__ float s_sum[4];

    const int n = blockIdx.x;
    const int t = threadIdx.x;
    const int lane = t & 63;
    const int wid = t >> 6;         // wave id == head in phase 0
    const int grp = t >> 5;         // phase-1 group (edge parity)
    const int gl  = t & 31;         // lane in group; channels gl*8..gl*8+7
    const int h3  = gl >> 3;        // head owning those channels
    const int start = rowptr[n];
    const int deg = rowptr[n + 1] - start;
    const float ad = adst[n * 4 + wid];

    float ssum = 0.f;
    float acc[8] = {0.f, 0.f, 0.f, 0.f, 0.f, 0.f, 0.f, 0.f};

    for (int c0 = 0; c0 < deg; c0 += ACHUNK) {
        const int cn = min(ACHUNK, deg - c0);
        if (c0) __syncthreads();
        for (int e = lane; e < cn; e += 64) {
            int src = csr_src[start + c0 + e];
            if (wid == 0) s_src[e] = src;
            float sc = asrc[src * 4 + wid] + ad;
            sc = (sc >= 0.f) ? sc : 0.2f * sc;   // leaky relu 0.2
            float w = __expf(sc);
            s_w[e][wid] = w;
            ssum += w;
        }
        __syncthreads();
        #pragma unroll 2
        for (int e = grp; e < cn; e += 8) {
            float w = s_w[e][h3];
            uint4 v = *reinterpret_cast<const uint4*>(&h[(size_t)s_src[e] * HC + gl * 8]);
            acc[0] = fmaf(w, bflo(v.x), acc[0]);
            acc[1] = fmaf(w, bfhi(v.x), acc[1]);
            acc[2] = fmaf(w, bflo(v.y), acc[2]);
            acc[3] = fmaf(w, bfhi(v.y), acc[3]);
            acc[4] = fmaf(w, bflo(v.z), acc[4]);
            acc[5] = fmaf(w, bfhi(v.z), acc[5]);
            acc[6] = fmaf(w, bflo(v.w), acc[6]);
            acc[7] = fmaf(w, bfhi(v.w), acc[7]);
        }
    }
    #pragma unroll
    for (int off = 1; off < 64; off <<= 1) ssum += __shfl_xor(ssum, off, 64);
    if (lane == 0) s_sum[wid] = ssum;
    #pragma unroll
    for (int j = 0; j < 8; j++) s_acc[grp][gl * 8 + j] = acc[j];
    __syncthreads();
    float tot = 0.f;
    #pragma unroll
    for (int g = 0; g < 8; g++) tot += s_acc[g][t];
    float r = tot / s_sum[t >> 6] + bias[t];
    if (do_relu) r = fmaxf(r, 0.f);
    out[(size_t)n * HC + t] = __float2bfloat16(r);
}

// ---------------- pooling (batch sorted) ----------------

__global__ void graph_bounds_kernel(const int* __restrict__ batch, int* __restrict__ cnt) {
    int g = threadIdx.x;
    if (g >= N_GRAPH) return;
    int lo = 0, hi = N_NODES;
    while (lo < hi) { int mid = (lo + hi) >> 1; if (batch[mid] < g) lo = mid + 1; else hi = mid; }
    int start = lo;
    lo = 0; hi = N_NODES;
    while (lo < hi) { int mid = (lo + hi) >> 1; if (batch[mid] < g + 1) lo = mid + 1; else hi = mid; }
    cnt[g] = lo - start;
}

__global__ void pool_kernel(const __hip_bfloat16* __restrict__ h, const int* __restrict__ batch,
                            float* __restrict__ pooled) {
    const int t = threadIdx.x;
    const int n0 = blockIdx.x * 256;
    if (n0 >= N_NODES) return;
    const int nend = min(n0 + 256, N_NODES);
    float acc = 0.f;
    int cur = batch[n0];
    for (int n = n0; n < nend; ++n) {
        int g = batch[n];
        if (g != cur) {
            atomicAdd(&pooled[cur * 256 + t], acc);
            acc = 0.f;
            cur = g;
        }
        acc += __bfloat162float(h[(size_t)n * 256 + t]);
    }
    atomicAdd(&pooled[cur * 256 + t], acc);
}

// ---------------- MLP head ----------------

__global__ __launch_bounds__(1024)
void mlp1_kernel(const float* __restrict__ pooled, const int* __restrict__ cnt,
                 const float* __restrict__ W, const float* __restrict__ b,
                 float* __restrict__ hidden) {
    __shared__ float row[256];
    const int g = blockIdx.x, t = threadIdx.x;
    if (t < 256) {
        float c = (float)max(cnt[g], 1);
        row[t] = pooled[g * 256 + t] / c;
    }
    __syncthreads();
    float acc = b[t];
    for (int k = 0; k < 256; k++) acc = fmaf(row[k], W[(size_t)k * NHID + t], acc);
    hidden[g * NHID + t] = fmaxf(acc, 0.f);
}

__global__ __launch_bounds__(768)
void mlp2_kernel(const float* __restrict__ hidden, const float* __restrict__ W,
                 const float* __restrict__ b, float* __restrict__ out) {
    __shared__ float row[NHID];
    const int g = blockIdx.x, t = threadIdx.x;
    row[t] = hidden[g * NHID + t];
    if (t < NHID - NOUT) row[NOUT + t] = hidden[g * NHID + NOUT + t];
    __syncthreads();
    float acc = b[t];
    for (int k = 0; k < NHID; k++) acc = fmaf(row[k], W[(size_t)k * NOUT + t], acc);
    out[g * NOUT + t] = acc;
}

// ---------------- launch ----------------

extern "C" void kernel_launch(void* const* d_in, const int* in_sizes, int n_in,
                              void* d_out, int out_size, void* d_ws, size_t ws_size,
                              hipStream_t stream) {
    const float* x  = (const float*)d_in[0];
    const int* ei   = (const int*)d_in[1];
    const int* batch = (const int*)d_in[2];
    const float* W1 = (const float*)d_in[3];
    const float* as1 = (const float*)d_in[4];
    const float* ad1 = (const float*)d_in[5];
    const float* b1 = (const float*)d_in[6];
    const float* W2 = (const float*)d_in[7];
    const float* as2 = (const float*)d_in[8];
    const float* ad2 = (const float*)d_in[9];
    const float* b2 = (const float*)d_in[10];
    const float* W3 = (const float*)d_in[11];
    const float* as3 = (const float*)d_in[12];
    const float* ad3 = (const float*)d_in[13];
    const float* b3 = (const float*)d_in[14];
    const float* Wm1 = (const float*)d_in[15];
    const float* bm1 = (const float*)d_in[16];
    const float* Wm2 = (const float*)d_in[17];
    const float* bm2 = (const float*)d_in[18];
    float* out = (float*)d_out;

    char* base = (char*)d_ws;
    size_t off = 0;
    auto alloc = [&](size_t bytes) { char* p = base + off; off = (off + bytes + 255) & ~(size_t)255; return p; };
    __hip_bfloat16* x_bf = (__hip_bfloat16*)alloc((size_t)N_NODES * 256 * 2);
    __hip_bfloat16* hA   = (__hip_bfloat16*)alloc((size_t)N_NODES * 256 * 2);
    __hip_bfloat16* hB   = (__hip_bfloat16*)alloc((size_t)N_NODES * 256 * 2);
    __hip_bfloat16* Wt1  = (__hip_bfloat16*)alloc((size_t)256 * 256 * 2);
    __hip_bfloat16* Wt2  = (__hip_bfloat16*)alloc((size_t)256 * 256 * 2);
    __hip_bfloat16* Wt3  = (__hip_bfloat16*)alloc((size_t)256 * 256 * 2);
    float* asrc   = (float*)alloc((size_t)N_NODES * 4 * 4);
    float* adst   = (float*)alloc((size_t)N_NODES * 4 * 4);
    int*   deg    = (int*)alloc((size_t)N_NODES * 4);
    int*   cursor = (int*)alloc((size_t)N_NODES * 4);
    int*   rowptr = (int*)alloc((size_t)(N_NODES + 1) * 4);
    int*   bsum   = (int*)alloc((size_t)SCAN_NB * 4);
    int*   csrsrc = (int*)alloc((size_t)E_TOT * 4);
    float* pooled = (float*)alloc((size_t)N_GRAPH * 256 * 4);
    int*   cnt    = (int*)alloc((size_t)N_GRAPH * 4);
    float* hidden = (float*)alloc((size_t)N_GRAPH * NHID * 4);
    (void)ws_size; (void)n_in; (void)in_sizes; (void)out_size;

    hipMemsetAsync(deg, 0, (size_t)N_NODES * 4, stream);
    hipMemsetAsync(cursor, 0, (size_t)N_NODES * 4, stream);
    hipMemsetAsync(pooled, 0, (size_t)N_GRAPH * 256 * 4, stream);

    // dtype prep
    cast_x_kernel<<<(N_NODES * 256 / 4 + 255) / 256, 256, 0, stream>>>(x, x_bf);
    conv_wt_kernel<<<256, 256, 0, stream>>>(W1, Wt1);
    conv_wt_kernel<<<256, 256, 0, stream>>>(W2, Wt2);
    conv_wt_kernel<<<256, 256, 0, stream>>>(W3, Wt3);

    // CSR (multi-block scan)
    const int eb = (E_TOT + 255) / 256;
    count_deg_kernel<<<eb, 256, 0, stream>>>(ei, deg);
    scan_p1_kernel<<<SCAN_NB, 256, 0, stream>>>(deg, bsum);
    scan_p2_kernel<<<1, 256, 0, stream>>>(bsum);
    scan_p3_kernel<<<SCAN_NB, 256, 0, stream>>>(deg, bsum, rowptr);
    fill_csr_kernel<<<eb, 256, 0, stream>>>(ei, rowptr, cursor, csrsrc);

    dim3 ggrid((N_NODES + GBM - 1) / GBM, 256 / GBN);

    // layer 1
    gemm_mfma_kernel<<<ggrid, 256, 0, stream>>>(x_bf, Wt1, hA, N_NODES, as1, ad1, asrc, adst);
    gat_fused_agg<<<N_NODES, 256, 0, stream>>>(hA, asrc, adst, rowptr, csrsrc, b1, hB, 1);
    // layer 2
    gemm_mfma_kernel<<<ggrid, 256, 0, stream>>>(hB, Wt2, hA, N_NODES, as2, ad2, asrc, adst);
    gat_fused_agg<<<N_NODES, 256, 0, stream>>>(hA, asrc, adst, rowptr, csrsrc, b2, hB, 1);
    // layer 3
    gemm_mfma_kernel<<<ggrid, 256, 0, stream>>>(hB, Wt3, hA, N_NODES, as3, ad3, asrc, adst);
    gat_fused_agg<<<N_NODES, 256, 0, stream>>>(hA, asrc, adst, rowptr, csrsrc, b3, hB, 0);

    // pool + MLP
    graph_bounds_kernel<<<1, 64, 0, stream>>>(batch, cnt);
    pool_kernel<<<(N_NODES + 255) / 256, 256, 0, stream>>>(hB, batch, pooled);
    mlp1_kernel<<<N_GRAPH, 1024, 0, stream>>>(pooled, cnt, Wm1, bm1, hidden);
    mlp2_kernel<<<N_GRAPH, NOUT, 0, stream>>>(hidden, Wm2, bm2, out);
}

// Round 7
// 417.268 us; speedup vs baseline: 2.7764x; 1.0970x over previous
//
#include <hip/hip_runtime.h>
#include <hip/hip_bf16.h>
#include <math.h>

#define N_NODES 40000
#define N_EDGES 640000
#define N_GRAPH 64
#define HEADS 4
#define CHAN 64
#define HC 256          // HEADS*CHAN
#define NHID 1024
#define NOUT 768
#define E_TOT (N_EDGES + N_NODES)
#define SCAN_NB ((N_NODES + 255) / 256)   // 157

typedef __attribute__((ext_vector_type(8))) short bf16x8;
typedef __attribute__((ext_vector_type(4))) float f32x4;

__device__ inline float bflo(unsigned u) { return __uint_as_float(u << 16); }
__device__ inline float bfhi(unsigned u) { return __uint_as_float(u & 0xffff0000u); }

// ---------------- dtype conversion ----------------

__global__ void cast_x_kernel(const float* __restrict__ x, __hip_bfloat16* __restrict__ xb) {
    int i = blockIdx.x * blockDim.x + threadIdx.x;      // handles 4 elems
    float4 v = *reinterpret_cast<const float4*>(&x[(size_t)i * 4]);
    __hip_bfloat16 o[4] = {__float2bfloat16(v.x), __float2bfloat16(v.y),
                           __float2bfloat16(v.z), __float2bfloat16(v.w)};
    *reinterpret_cast<ushort4*>(&xb[(size_t)i * 4]) = *reinterpret_cast<ushort4*>(o);
}

// Wt[n][k] = bf16(W[k][n])  (transposed so GEMM B-fragments are contiguous)
__global__ void conv_wt_kernel(const float* __restrict__ W, __hip_bfloat16* __restrict__ Wt) {
    int k = blockIdx.x, n = threadIdx.x;
    Wt[(size_t)n * 256 + k] = __float2bfloat16(W[(size_t)k * 256 + n]);
}

// ---------------- CSR build ----------------

__global__ void count_deg_kernel(const int* __restrict__ ei, int* __restrict__ deg) {
    int i = blockIdx.x * blockDim.x + threadIdx.x;
    if (i >= E_TOT) return;
    int dst = (i < N_EDGES) ? ei[N_EDGES + i] : (i - N_EDGES);
    atomicAdd(&deg[dst], 1);
}

// ---- multi-block exclusive scan of deg -> rowptr (3 phases) ----

__global__ __launch_bounds__(256)
void scan_p1_kernel(const int* __restrict__ deg, int* __restrict__ bsum) {
    const int b = blockIdx.x, t = threadIdx.x;
    const int i = b * 256 + t;
    int v = (i < N_NODES) ? deg[i] : 0;
    #pragma unroll
    for (int off = 1; off < 64; off <<= 1) v += __shfl_xor(v, off, 64);
    __shared__ int ws[4];
    if ((t & 63) == 0) ws[t >> 6] = v;
    __syncthreads();
    if (t == 0) bsum[b] = ws[0] + ws[1] + ws[2] + ws[3];
}

__global__ __launch_bounds__(256)
void scan_p2_kernel(int* __restrict__ bsum) {     // single block; SCAN_NB <= 256
    __shared__ int s[256];
    const int t = threadIdx.x;
    int v = (t < SCAN_NB) ? bsum[t] : 0;
    s[t] = v;
    __syncthreads();
    #pragma unroll
    for (int off = 1; off < 256; off <<= 1) {
        int x = (t >= off) ? s[t - off] : 0;
        __syncthreads();
        s[t] += x;
        __syncthreads();
    }
    if (t < SCAN_NB) bsum[t] = s[t] - v;          // exclusive block offset
}

__global__ __launch_bounds__(256)
void scan_p3_kernel(const int* __restrict__ deg, const int* __restrict__ bsum,
                    int* __restrict__ rowptr) {
    __shared__ int s[256];
    const int b = blockIdx.x, t = threadIdx.x;
    const int i = b * 256 + t;
    int v = (i < N_NODES) ? deg[i] : 0;
    s[t] = v;
    __syncthreads();
    #pragma unroll
    for (int off = 1; off < 256; off <<= 1) {
        int x = (t >= off) ? s[t - off] : 0;
        __syncthreads();
        s[t] += x;
        __syncthreads();
    }
    if (i < N_NODES) rowptr[i] = bsum[b] + s[t] - v;
    if (i == 0) rowptr[N_NODES] = E_TOT;          // total is static
}

__global__ void fill_csr_kernel(const int* __restrict__ ei, const int* __restrict__ rowptr,
                                int* __restrict__ cursor, int* __restrict__ csr_src) {
    int i = blockIdx.x * blockDim.x + threadIdx.x;
    if (i >= E_TOT) return;
    int src, dst;
    if (i < N_EDGES) { src = ei[i]; dst = ei[N_EDGES + i]; }
    else             { src = dst = i - N_EDGES; }
    int pos = atomicAdd(&cursor[dst], 1);
    csr_src[rowptr[dst] + pos] = src;
}

// ---------------- bf16 MFMA GEMM + fused alpha epilogue ----------------

#define GBM 128
#define GBN 128
#define GBK 32

__global__ __launch_bounds__(256)
void gemm_mfma_kernel(const __hip_bfloat16* __restrict__ A, const __hip_bfloat16* __restrict__ Wt,
                      __hip_bfloat16* __restrict__ C, int nrows,
                      const float* __restrict__ a_s, const float* __restrict__ a_d,
                      float* __restrict__ asrc, float* __restrict__ adst) {
    __shared__ ushort A_lds[128][40];   // [row][k], pad 32->40 keeps 16B align
    __shared__ ushort B_lds[128][40];   // [col][k]
    const int tid = threadIdx.x;
    const int lane = tid & 63;
    const int l15 = lane & 15;
    const int lq  = lane >> 4;
    const int wid = tid >> 6;
    const int wrow = (wid >> 1) * 64;
    const int wcol = (wid & 1) * 64;
    const int row0 = blockIdx.x * GBM;
    const int col0 = blockIdx.y * GBN;

    f32x4 acc[4][4];
    #pragma unroll
    for (int m = 0; m < 4; m++)
        #pragma unroll
        for (int n = 0; n < 4; n++)
            acc[m][n] = (f32x4){0.f, 0.f, 0.f, 0.f};

    const char* Ab = (const char*)A;
    const char* Wb = (const char*)Wt;

    for (int kt = 0; kt < 256; kt += GBK) {
        __syncthreads();
        #pragma unroll
        for (int i = 0; i < 2; i++) {
            int ch = tid + i * 256;
            int r = ch >> 2, sl = ch & 3;
            int arow = row0 + r; if (arow >= nrows) arow = nrows - 1;
            uint4 va = *reinterpret_cast<const uint4*>(Ab + (size_t)arow * 512 + kt * 2 + sl * 16);
            *reinterpret_cast<uint4*>(&A_lds[r][sl * 8]) = va;
            uint4 vb = *reinterpret_cast<const uint4*>(Wb + (size_t)(col0 + r) * 512 + kt * 2 + sl * 16);
            *reinterpret_cast<uint4*>(&B_lds[r][sl * 8]) = vb;
        }
        __syncthreads();
        bf16x8 af[4], bfr[4];
        #pragma unroll
        for (int m = 0; m < 4; m++)
            af[m] = *reinterpret_cast<const bf16x8*>(&A_lds[wrow + m * 16 + l15][lq * 8]);
        #pragma unroll
        for (int n = 0; n < 4; n++)
            bfr[n] = *reinterpret_cast<const bf16x8*>(&B_lds[wcol + n * 16 + l15][lq * 8]);
        #pragma unroll
        for (int m = 0; m < 4; m++)
            #pragma unroll
            for (int n = 0; n < 4; n++)
                acc[m][n] = __builtin_amdgcn_mfma_f32_16x16x32_bf16(af[m], bfr[n], acc[m][n], 0, 0, 0);
    }

    const int head = (col0 + wcol) >> 6;
    float was[4], wad[4];
    #pragma unroll
    for (int n = 0; n < 4; n++) {
        was[n] = a_s[head * 64 + n * 16 + l15];
        wad[n] = a_d[head * 64 + n * 16 + l15];
    }
    #pragma unroll
    for (int m = 0; m < 4; m++) {
        #pragma unroll
        for (int reg = 0; reg < 4; reg++) {
            float ps = 0.f, pd = 0.f;
            #pragma unroll
            for (int n = 0; n < 4; n++) {
                float v = acc[m][n][reg];
                ps = fmaf(v, was[n], ps);
                pd = fmaf(v, wad[n], pd);
            }
            #pragma unroll
            for (int off = 1; off < 16; off <<= 1) {
                ps += __shfl_xor(ps, off, 16);
                pd += __shfl_xor(pd, off, 16);
            }
            int row = row0 + wrow + m * 16 + lq * 4 + reg;
            if (l15 == 0 && row < nrows) {
                asrc[row * 4 + head] = ps;
                adst[row * 4 + head] = pd;
            }
        }
        #pragma unroll
        for (int n = 0; n < 4; n++) {
            int col = col0 + wcol + n * 16 + l15;
            #pragma unroll
            for (int reg = 0; reg < 4; reg++) {
                int row = row0 + wrow + m * 16 + lq * 4 + reg;
                if (row < nrows)
                    C[(size_t)row * 256 + col] = __float2bfloat16(acc[m][n][reg]);
            }
        }
    }
}

// ---------------- fused edge-softmax + aggregation (max-free, wave-per-head) ----------------

#define ACHUNK 256

__global__ __launch_bounds__(256)
void gat_fused_agg(const __hip_bfloat16* __restrict__ h, const float* __restrict__ asrc,
                   const float* __restrict__ adst, const int* __restrict__ rowptr,
                   const int* __restrict__ csr_src, const float* __restrict__ bias,
                   __hip_bfloat16* __restrict__ out, int do_relu) {
    __shared__ int   s_src[ACHUNK];
    __shared__ float s_w[ACHUNK][5];    // pad 4->5: conflict-free phase-0 writes
    __shared__ float s_acc[8][HC];
    __shared__ float s_sum[4];

    const int n = blockIdx.x;
    const int t = threadIdx.x;
    const int lane = t & 63;
    const int wid = t >> 6;         // wave id == head in phase 0
    const int grp = t >> 5;         // phase-1 group (edge parity)
    const int gl  = t & 31;         // lane in group; channels gl*8..gl*8+7
    const int h3  = gl >> 3;        // head owning those channels
    const int start = rowptr[n];
    const int deg = rowptr[n + 1] - start;
    const float ad = adst[n * 4 + wid];

    float ssum = 0.f;
    float acc[8] = {0.f, 0.f, 0.f, 0.f, 0.f, 0.f, 0.f, 0.f};

    for (int c0 = 0; c0 < deg; c0 += ACHUNK) {
        const int cn = min(ACHUNK, deg - c0);
        if (c0) __syncthreads();
        for (int e = lane; e < cn; e += 64) {
            int src = csr_src[start + c0 + e];
            if (wid == 0) s_src[e] = src;
            float sc = asrc[src * 4 + wid] + ad;
            sc = (sc >= 0.f) ? sc : 0.2f * sc;   // leaky relu 0.2
            float w = __expf(sc);
            s_w[e][wid] = w;
            ssum += w;
        }
        __syncthreads();
        #pragma unroll 2
        for (int e = grp; e < cn; e += 8) {
            float w = s_w[e][h3];
            uint4 v = *reinterpret_cast<const uint4*>(&h[(size_t)s_src[e] * HC + gl * 8]);
            acc[0] = fmaf(w, bflo(v.x), acc[0]);
            acc[1] = fmaf(w, bfhi(v.x), acc[1]);
            acc[2] = fmaf(w, bflo(v.y), acc[2]);
            acc[3] = fmaf(w, bfhi(v.y), acc[3]);
            acc[4] = fmaf(w, bflo(v.z), acc[4]);
            acc[5] = fmaf(w, bfhi(v.z), acc[5]);
            acc[6] = fmaf(w, bflo(v.w), acc[6]);
            acc[7] = fmaf(w, bfhi(v.w), acc[7]);
        }
    }
    #pragma unroll
    for (int off = 1; off < 64; off <<= 1) ssum += __shfl_xor(ssum, off, 64);
    if (lane == 0) s_sum[wid] = ssum;
    #pragma unroll
    for (int j = 0; j < 8; j++) s_acc[grp][gl * 8 + j] = acc[j];
    __syncthreads();
    float tot = 0.f;
    #pragma unroll
    for (int g = 0; g < 8; g++) tot += s_acc[g][t];
    float r = tot / s_sum[t >> 6] + bias[t];
    if (do_relu) r = fmaxf(r, 0.f);
    out[(size_t)n * HC + t] = __float2bfloat16(r);
}

// ---------------- pooling (batch sorted): one block per graph, no atomics ----------------

__global__ void graph_bounds_kernel(const int* __restrict__ batch, int* __restrict__ cnt) {
    int g = threadIdx.x;
    if (g >= N_GRAPH) return;
    int lo = 0, hi = N_NODES;
    while (lo < hi) { int mid = (lo + hi) >> 1; if (batch[mid] < g) lo = mid + 1; else hi = mid; }
    int start = lo;
    lo = 0; hi = N_NODES;
    while (lo < hi) { int mid = (lo + hi) >> 1; if (batch[mid] < g + 1) lo = mid + 1; else hi = mid; }
    cnt[g] = lo - start;
}

__global__ __launch_bounds__(256)
void pool_kernel(const __hip_bfloat16* __restrict__ h, const int* __restrict__ batch,
                 float* __restrict__ pooled) {
    __shared__ float s_acc[8][HC];
    const int g = blockIdx.x;
    const int t = threadIdx.x;
    const int grp = t >> 5;         // 8 node-parity groups
    const int gl  = t & 31;         // lane -> channels gl*8..gl*8+7
    // bounds via binary search (all threads redundantly; ~34 L2-hit loads)
    int lo = 0, hi = N_NODES;
    while (lo < hi) { int mid = (lo + hi) >> 1; if (batch[mid] < g) lo = mid + 1; else hi = mid; }
    const int start = lo;
    lo = 0; hi = N_NODES;
    while (lo < hi) { int mid = (lo + hi) >> 1; if (batch[mid] < g + 1) lo = mid + 1; else hi = mid; }
    const int end = lo;

    float acc[8] = {0.f, 0.f, 0.f, 0.f, 0.f, 0.f, 0.f, 0.f};
    for (int n = start + grp; n < end; n += 8) {
        uint4 v = *reinterpret_cast<const uint4*>(&h[(size_t)n * HC + gl * 8]);
        acc[0] += bflo(v.x); acc[1] += bfhi(v.x);
        acc[2] += bflo(v.y); acc[3] += bfhi(v.y);
        acc[4] += bflo(v.z); acc[5] += bfhi(v.z);
        acc[6] += bflo(v.w); acc[7] += bfhi(v.w);
    }
    #pragma unroll
    for (int j = 0; j < 8; j++) s_acc[grp][gl * 8 + j] = acc[j];
    __syncthreads();
    float tot = 0.f;
    #pragma unroll
    for (int q = 0; q < 8; q++) tot += s_acc[q][t];
    pooled[g * HC + t] = tot;
}

// ---------------- MLP head ----------------

__global__ __launch_bounds__(1024)
void mlp1_kernel(const float* __restrict__ pooled, const int* __restrict__ cnt,
                 const float* __restrict__ W, const float* __restrict__ b,
                 float* __restrict__ hidden) {
    __shared__ float row[256];
    const int g = blockIdx.x, t = threadIdx.x;
    if (t < 256) {
        float c = (float)max(cnt[g], 1);
        row[t] = pooled[g * 256 + t] / c;
    }
    __syncthreads();
    float acc = b[t];
    for (int k = 0; k < 256; k++) acc = fmaf(row[k], W[(size_t)k * NHID + t], acc);
    hidden[g * NHID + t] = fmaxf(acc, 0.f);
}

__global__ __launch_bounds__(768)
void mlp2_kernel(const float* __restrict__ hidden, const float* __restrict__ W,
                 const float* __restrict__ b, float* __restrict__ out) {
    __shared__ float row[NHID];
    const int g = blockIdx.x, t = threadIdx.x;
    row[t] = hidden[g * NHID + t];
    if (t < NHID - NOUT) row[NOUT + t] = hidden[g * NHID + NOUT + t];
    __syncthreads();
    float acc = b[t];
    for (int k = 0; k < NHID; k++) acc = fmaf(row[k], W[(size_t)k * NOUT + t], acc);
    out[g * NOUT + t] = acc;
}

// ---------------- launch ----------------

extern "C" void kernel_launch(void* const* d_in, const int* in_sizes, int n_in,
                              void* d_out, int out_size, void* d_ws, size_t ws_size,
                              hipStream_t stream) {
    const float* x  = (const float*)d_in[0];
    const int* ei   = (const int*)d_in[1];
    const int* batch = (const int*)d_in[2];
    const float* W1 = (const float*)d_in[3];
    const float* as1 = (const float*)d_in[4];
    const float* ad1 = (const float*)d_in[5];
    const float* b1 = (const float*)d_in[6];
    const float* W2 = (const float*)d_in[7];
    const float* as2 = (const float*)d_in[8];
    const float* ad2 = (const float*)d_in[9];
    const float* b2 = (const float*)d_in[10];
    const float* W3 = (const float*)d_in[11];
    const float* as3 = (const float*)d_in[12];
    const float* ad3 = (const float*)d_in[13];
    const float* b3 = (const float*)d_in[14];
    const float* Wm1 = (const float*)d_in[15];
    const float* bm1 = (const float*)d_in[16];
    const float* Wm2 = (const float*)d_in[17];
    const float* bm2 = (const float*)d_in[18];
    float* out = (float*)d_out;

    char* base = (char*)d_ws;
    size_t off = 0;
    auto alloc = [&](size_t bytes) { char* p = base + off; off = (off + bytes + 255) & ~(size_t)255; return p; };
    __hip_bfloat16* x_bf = (__hip_bfloat16*)alloc((size_t)N_NODES * 256 * 2);
    __hip_bfloat16* hA   = (__hip_bfloat16*)alloc((size_t)N_NODES * 256 * 2);
    __hip_bfloat16* hB   = (__hip_bfloat16*)alloc((size_t)N_NODES * 256 * 2);
    __hip_bfloat16* Wt1  = (__hip_bfloat16*)alloc((size_t)256 * 256 * 2);
    __hip_bfloat16* Wt2  = (__hip_bfloat16*)alloc((size_t)256 * 256 * 2);
    __hip_bfloat16* Wt3  = (__hip_bfloat16*)alloc((size_t)256 * 256 * 2);
    float* asrc   = (float*)alloc((size_t)N_NODES * 4 * 4);
    float* adst   = (float*)alloc((size_t)N_NODES * 4 * 4);
    int*   deg    = (int*)alloc((size_t)N_NODES * 4);
    int*   cursor = (int*)alloc((size_t)N_NODES * 4);
    int*   rowptr = (int*)alloc((size_t)(N_NODES + 1) * 4);
    int*   bsum   = (int*)alloc((size_t)SCAN_NB * 4);
    int*   csrsrc = (int*)alloc((size_t)E_TOT * 4);
    float* pooled = (float*)alloc((size_t)N_GRAPH * 256 * 4);
    int*   cnt    = (int*)alloc((size_t)N_GRAPH * 4);
    float* hidden = (float*)alloc((size_t)N_GRAPH * NHID * 4);
    (void)ws_size; (void)n_in; (void)in_sizes; (void)out_size;

    hipMemsetAsync(deg, 0, (size_t)N_NODES * 4, stream);
    hipMemsetAsync(cursor, 0, (size_t)N_NODES * 4, stream);

    // dtype prep
    cast_x_kernel<<<(N_NODES * 256 / 4 + 255) / 256, 256, 0, stream>>>(x, x_bf);
    conv_wt_kernel<<<256, 256, 0, stream>>>(W1, Wt1);
    conv_wt_kernel<<<256, 256, 0, stream>>>(W2, Wt2);
    conv_wt_kernel<<<256, 256, 0, stream>>>(W3, Wt3);

    // CSR (multi-block scan)
    const int eb = (E_TOT + 255) / 256;
    count_deg_kernel<<<eb, 256, 0, stream>>>(ei, deg);
    scan_p1_kernel<<<SCAN_NB, 256, 0, stream>>>(deg, bsum);
    scan_p2_kernel<<<1, 256, 0, stream>>>(bsum);
    scan_p3_kernel<<<SCAN_NB, 256, 0, stream>>>(deg, bsum, rowptr);
    fill_csr_kernel<<<eb, 256, 0, stream>>>(ei, rowptr, cursor, csrsrc);

    dim3 ggrid((N_NODES + GBM - 1) / GBM, 256 / GBN);

    // layer 1
    gemm_mfma_kernel<<<ggrid, 256, 0, stream>>>(x_bf, Wt1, hA, N_NODES, as1, ad1, asrc, adst);
    gat_fused_agg<<<N_NODES, 256, 0, stream>>>(hA, asrc, adst, rowptr, csrsrc, b1, hB, 1);
    // layer 2
    gemm_mfma_kernel<<<ggrid, 256, 0, stream>>>(hB, Wt2, hA, N_NODES, as2, ad2, asrc, adst);
    gat_fused_agg<<<N_NODES, 256, 0, stream>>>(hA, asrc, adst, rowptr, csrsrc, b2, hB, 1);
    // layer 3
    gemm_mfma_kernel<<<ggrid, 256, 0, stream>>>(hB, Wt3, hA, N_NODES, as3, ad3, asrc, adst);
    gat_fused_agg<<<N_NODES, 256, 0, stream>>>(hA, asrc, adst, rowptr, csrsrc, b3, hB, 0);

    // pool + MLP
    graph_bounds_kernel<<<1, 64, 0, stream>>>(batch, cnt);
    pool_kernel<<<N_GRAPH, 256, 0, stream>>>(hB, batch, pooled);
    mlp1_kernel<<<N_GRAPH, 1024, 0, stream>>>(pooled, cnt, Wm1, bm1, hidden);
    mlp2_kernel<<<N_GRAPH, NOUT, 0, stream>>>(hidden, Wm2, bm2, out);
}